// Round 1
// baseline (1514.248 us; speedup 1.0000x reference)
//
#include <hip/hip_runtime.h>
#include <math.h>

#define NN   10000   // nodes
#define NE   160000  // edges
#define CCH  64      // in/out channels
#define TIN  12      // input time steps
#define HCH  64      // hidden channels
#define TSP  10      // T - 2
#define FF   640     // H * TSP
#define TOUT 8       // TSP - 2

// ---------------- TCN1: x[N,64,12] -> out[N, 64*10] (f = h*10 + t) ----------
__global__ void k_tcn1(const float* __restrict__ x, const float* __restrict__ w1,
                       const float* __restrict__ b1, const float* __restrict__ w2,
                       const float* __restrict__ b2, float* __restrict__ out)
{
    __shared__ float xs[4][CCH * TIN];   // 4 nodes * 768 floats = 12 KB
    int node0 = blockIdx.x * 4;
    for (int i = threadIdx.x; i < 4 * CCH * TIN; i += 256) {
        int nn = i / (CCH * TIN), off = i % (CCH * TIN);
        int g = node0 + nn;
        xs[nn][off] = (g < NN) ? x[(size_t)g * CCH * TIN + off] : 0.f;
    }
    __syncthreads();
    int ln = threadIdx.x >> 6, h = threadIdx.x & 63;
    int node = node0 + ln;
    if (node >= NN) return;
    float s1[TSP], s2[TSP];
    float bb1 = b1[h], bb2 = b2[h];
#pragma unroll
    for (int t = 0; t < TSP; ++t) { s1[t] = bb1; s2[t] = bb2; }
    for (int c = 0; c < CCH; ++c) {
        const float* wp1 = &w1[(h * CCH + c) * 3];
        const float* wp2 = &w2[(h * CCH + c) * 3];
        float a0 = wp1[0], a1 = wp1[1], a2 = wp1[2];
        float g0 = wp2[0], g1 = wp2[1], g2 = wp2[2];
        const float* xr = &xs[ln][c * TIN];
        float v[TIN];
#pragma unroll
        for (int t = 0; t < TIN; ++t) v[t] = xr[t];
#pragma unroll
        for (int t = 0; t < TSP; ++t) {
            s1[t] += a0 * v[t] + a1 * v[t + 1] + a2 * v[t + 2];
            s2[t] += g0 * v[t] + g1 * v[t + 1] + g2 * v[t + 2];
        }
    }
#pragma unroll
    for (int t = 0; t < TSP; ++t) {
        float val = tanhf(s1[t]) * (1.f / (1.f + expf(-s2[t])));
        out[(size_t)node * FF + h * TSP + t] = val;
    }
}

// ---------------- psi MLP: ND[N,3] -> psi[N,3] ------------------------------
__global__ void k_psi(const float* __restrict__ ND, const float* __restrict__ W1,
                      const float* __restrict__ b1, const float* __restrict__ W2,
                      const float* __restrict__ b2, float* __restrict__ psi)
{
    int n = blockIdx.x * blockDim.x + threadIdx.x;
    if (n >= NN) return;
    float d0 = ND[n * 3], d1 = ND[n * 3 + 1], d2 = ND[n * 3 + 2];
    float o0 = b2[0], o1 = b2[1], o2 = b2[2];
    for (int j = 0; j < 64; ++j) {
        float hv = d0 * W1[j] + d1 * W1[64 + j] + d2 * W1[128 + j] + b1[j];
        hv = fmaxf(hv, 0.f);
        o0 += hv * W2[j * 3 + 0];
        o1 += hv * W2[j * 3 + 1];
        o2 += hv * W2[j * 3 + 2];
    }
    psi[n * 3 + 0] = o0; psi[n * 3 + 1] = o1; psi[n * 3 + 2] = o2;
}

// ---------------- degree / counts -------------------------------------------
__global__ void k_deg(const int* __restrict__ ei, const float* __restrict__ ea,
                      int* __restrict__ cnt, float* __restrict__ degp, float* __restrict__ degn)
{
    int e = blockIdx.x * blockDim.x + threadIdx.x;
    if (e >= NE) return;
    int d = ei[NE + e];
    atomicAdd(&cnt[d], 1);
    atomicAdd(&degp[d], ea[e * 2 + 0] + 1.f);
    atomicAdd(&degn[d], ea[e * 2 + 1] + 1.f);
}

__global__ void k_dis(const float* __restrict__ degp, const float* __restrict__ degn,
                      float* __restrict__ disp, float* __restrict__ disn)
{
    int n = blockIdx.x * blockDim.x + threadIdx.x;
    if (n >= NN) return;
    disp[n] = 1.f / sqrtf(degp[n] + 1.f);   // +1: self loop weight
    disn[n] = 1.f / sqrtf(degn[n] + 1.f);
}

// ---------------- exclusive scan of counts -> rowptr ------------------------
__global__ __launch_bounds__(1024) void k_scan(const int* __restrict__ cnt, int* __restrict__ rowptr)
{
    __shared__ int buf[1024];
    __shared__ int carry;
    if (threadIdx.x == 0) carry = 0;
    __syncthreads();
    for (int base = 0; base < NN; base += 1024) {
        int i = base + threadIdx.x;
        int v = (i < NN) ? cnt[i] : 0;
        buf[threadIdx.x] = v;
        __syncthreads();
        for (int off = 1; off < 1024; off <<= 1) {
            int t = (threadIdx.x >= (unsigned)off) ? buf[threadIdx.x - off] : 0;
            __syncthreads();
            buf[threadIdx.x] += t;
            __syncthreads();
        }
        if (i < NN) rowptr[i] = carry + buf[threadIdx.x] - v;
        __syncthreads();
        if (threadIdx.x == 0) carry += buf[1023];
        __syncthreads();
    }
    if (threadIdx.x == 0) rowptr[NN] = carry;
}

// ---------------- CSR fill ---------------------------------------------------
__global__ void k_fill(const int* __restrict__ ei, const float* __restrict__ ea,
                       const int* __restrict__ rowptr, int* __restrict__ cursor,
                       const float* __restrict__ disp, const float* __restrict__ disn,
                       int* __restrict__ colsrc, float* __restrict__ normp, float* __restrict__ normn)
{
    int e = blockIdx.x * blockDim.x + threadIdx.x;
    if (e >= NE) return;
    int s = ei[e], d = ei[NE + e];
    int slot = atomicAdd(&cursor[d], 1);
    int idx = rowptr[d] + slot;
    colsrc[idx] = s;
    normp[idx] = disp[s] * (ea[e * 2 + 0] + 1.f) * disp[d];
    normn[idx] = disn[s] * (ea[e * 2 + 1] + 1.f) * disn[d];
}

// ---------------- f32 GEMM: C[M,640] = A[M,640] @ B[640,640] ----------------
#define BM 128
#define BN 64
#define BK 16
__global__ __launch_bounds__(256) void k_gemm(const float* __restrict__ A,
                                              const float* __restrict__ B,
                                              float* __restrict__ Cm, int M)
{
    __shared__ float As[BK][BM];   // transposed: As[k][r]
    __shared__ float Bs[BK][BN];
    int tid = threadIdx.x;
    int row0 = blockIdx.x * BM;
    int col0 = blockIdx.y * BN;
    int tx = tid & 15, ty = tid >> 4;
    float acc[8][4] = {};
    int ar = tid >> 1;           // 0..127
    int ak = (tid & 1) * 8;      // 0 or 8
    int bk = tid >> 4;           // 0..15
    int bc = (tid & 15) * 4;     // 0..60
    for (int k0 = 0; k0 < FF; k0 += BK) {
        int grow = row0 + ar;
        float4 av0 = {0,0,0,0}, av1 = {0,0,0,0};
        if (grow < M) {
            av0 = *(const float4*)&A[(size_t)grow * FF + k0 + ak];
            av1 = *(const float4*)&A[(size_t)grow * FF + k0 + ak + 4];
        }
        float4 bv = *(const float4*)&B[(size_t)(k0 + bk) * FF + col0 + bc];
        __syncthreads();
        As[ak + 0][ar] = av0.x; As[ak + 1][ar] = av0.y;
        As[ak + 2][ar] = av0.z; As[ak + 3][ar] = av0.w;
        As[ak + 4][ar] = av1.x; As[ak + 5][ar] = av1.y;
        As[ak + 6][ar] = av1.z; As[ak + 7][ar] = av1.w;
        *(float4*)&Bs[bk][bc] = bv;
        __syncthreads();
#pragma unroll
        for (int k = 0; k < BK; ++k) {
            float4 a0 = *(const float4*)&As[k][ty * 8];
            float4 a1 = *(const float4*)&As[k][ty * 8 + 4];
            float4 b4 = *(const float4*)&Bs[k][tx * 4];
            float av[8] = {a0.x,a0.y,a0.z,a0.w,a1.x,a1.y,a1.z,a1.w};
            float bb[4] = {b4.x,b4.y,b4.z,b4.w};
#pragma unroll
            for (int i = 0; i < 8; ++i)
#pragma unroll
                for (int j = 0; j < 4; ++j)
                    acc[i][j] += av[i] * bb[j];
        }
    }
#pragma unroll
    for (int i = 0; i < 8; ++i) {
        int r = row0 + ty * 8 + i;
        if (r < M) {
            float4 o = {acc[i][0], acc[i][1], acc[i][2], acc[i][3]};
            *(float4*)&Cm[(size_t)r * FF + col0 + tx * 4] = o;
        }
    }
}

// ---------------- GCN aggregate: out[d] = relu(Anorm @ h + b); acc += psi*h --
__global__ void k_agg(const float* __restrict__ hsrc, const int* __restrict__ rowptr,
                      const int* __restrict__ colsrc, const float* __restrict__ enorm,
                      const float* __restrict__ dis, const float* __restrict__ bias,
                      float* __restrict__ hout, float* __restrict__ acc,
                      const float* __restrict__ psi, int hop)
{
    int d = blockIdx.x;
    int f = threadIdx.x;            // 640 threads
    float selfw = dis[d] * dis[d];
    float v = selfw * hsrc[(size_t)d * FF + f];
    int beg = rowptr[d], end = rowptr[d + 1];
    for (int idx = beg; idx < end; ++idx) {
        int s = colsrc[idx];
        float w = enorm[idx];
        v += w * hsrc[(size_t)s * FF + f];
    }
    v += bias[f];
    v = fmaxf(v, 0.f);
    hout[(size_t)d * FF + f] = v;
    if (acc) {
        float pv = psi[d * 3 + hop];
        if (hop == 0) acc[(size_t)d * FF + f] = pv * v;
        else          acc[(size_t)d * FF + f] += pv * v;
    }
}

// ---------------- GReTo mix: out[n,d,t] = relu(sum_c cat[n,c,t]*gW[c,d]+gb) --
__global__ void k_greto(const float* __restrict__ accb, const float* __restrict__ neg,
                        const float* __restrict__ gW, const float* __restrict__ gb,
                        float* __restrict__ out)
{
    __shared__ float sa[FF], sn[FF];
    int n = blockIdx.x;
    for (int i = threadIdx.x; i < FF; i += 640) {
        sa[i] = accb[(size_t)n * FF + i];
        sn[i] = neg[(size_t)n * FF + i];
    }
    __syncthreads();
    int t = threadIdx.x >> 6;       // 0..9, wave-uniform
    int d = threadIdx.x & 63;       // coalesced over gW
    float v = gb[d];
    for (int c = 0; c < HCH; ++c) {
        v += sa[c * TSP + t] * gW[c * HCH + d];
        v += sn[c * TSP + t] * gW[(HCH + c) * HCH + d];
    }
    out[(size_t)n * FF + d * TSP + t] = fmaxf(v, 0.f);
}

// ---------------- TCN2: g[N,64,10] -> out[N,64,8] ---------------------------
__global__ void k_tcn2(const float* __restrict__ g, const float* __restrict__ w1,
                       const float* __restrict__ b1, const float* __restrict__ w2,
                       const float* __restrict__ b2, float* __restrict__ out)
{
    __shared__ float xs[4][HCH * TSP];
    int node0 = blockIdx.x * 4;
    for (int i = threadIdx.x; i < 4 * HCH * TSP; i += 256) {
        int nn = i / (HCH * TSP), off = i % (HCH * TSP);
        int gg = node0 + nn;
        xs[nn][off] = (gg < NN) ? g[(size_t)gg * FF + off] : 0.f;
    }
    __syncthreads();
    int ln = threadIdx.x >> 6, c = threadIdx.x & 63;
    int node = node0 + ln;
    if (node >= NN) return;
    float s1[TOUT], s2[TOUT];
    float bb1 = b1[c], bb2 = b2[c];
#pragma unroll
    for (int t = 0; t < TOUT; ++t) { s1[t] = bb1; s2[t] = bb2; }
    for (int h = 0; h < HCH; ++h) {
        const float* wp1 = &w1[(c * HCH + h) * 3];
        const float* wp2 = &w2[(c * HCH + h) * 3];
        float a0 = wp1[0], a1 = wp1[1], a2 = wp1[2];
        float g0 = wp2[0], g1 = wp2[1], g2 = wp2[2];
        const float* xr = &xs[ln][h * TSP];
        float v[TSP];
#pragma unroll
        for (int t = 0; t < TSP; ++t) v[t] = xr[t];
#pragma unroll
        for (int t = 0; t < TOUT; ++t) {
            s1[t] += a0 * v[t] + a1 * v[t + 1] + a2 * v[t + 2];
            s2[t] += g0 * v[t] + g1 * v[t + 1] + g2 * v[t + 2];
        }
    }
#pragma unroll
    for (int t = 0; t < TOUT; ++t) {
        out[(size_t)node * (CCH * TOUT) + c * TOUT + t] =
            tanhf(s1[t]) * (1.f / (1.f + expf(-s2[t])));
    }
}

extern "C" void kernel_launch(void* const* d_in, const int* in_sizes, int n_in,
                              void* d_out, int out_size, void* d_ws, size_t ws_size,
                              hipStream_t stream)
{
    const float* x     = (const float*)d_in[0];
    const int*   ei    = (const int*)  d_in[1];
    const float* ea    = (const float*)d_in[2];
    const float* ndt   = (const float*)d_in[3];
    const float* tc1w1 = (const float*)d_in[4];
    const float* tc1b1 = (const float*)d_in[5];
    const float* tc1w2 = (const float*)d_in[6];
    const float* tc1b2 = (const float*)d_in[7];
    const float* Wpos  = (const float*)d_in[8];
    const float* bpos  = (const float*)d_in[9];
    const float* Wneg  = (const float*)d_in[10];
    const float* bneg  = (const float*)d_in[11];
    const float* greW  = (const float*)d_in[12];
    const float* greb  = (const float*)d_in[13];
    const float* psiW1 = (const float*)d_in[14];
    const float* psib1 = (const float*)d_in[15];
    const float* psiW2 = (const float*)d_in[16];
    const float* psib2 = (const float*)d_in[17];
    const float* tc2w1 = (const float*)d_in[18];
    const float* tc2b1 = (const float*)d_in[19];
    const float* tc2w2 = (const float*)d_in[20];
    const float* tc2b2 = (const float*)d_in[21];
    float* out = (float*)d_out;

    char* p = (char*)d_ws;
    float* out0  = (float*)p; p += (size_t)NN * FF * 4;
    float* bufB  = (float*)p; p += (size_t)NN * FF * 4;
    float* bufA  = (float*)p; p += (size_t)NN * FF * 4;
    float* accb  = (float*)p; p += (size_t)NN * FF * 4;
    float* psib  = (float*)p; p += (size_t)NN * 3 * 4;
    float* degp  = (float*)p; p += (size_t)NN * 4;
    float* degn  = (float*)p; p += (size_t)NN * 4;
    float* disp  = (float*)p; p += (size_t)NN * 4;
    float* disn  = (float*)p; p += (size_t)NN * 4;
    float* normp = (float*)p; p += (size_t)NE * 4;
    float* normn = (float*)p; p += (size_t)NE * 4;
    int* cnt     = (int*)p;   p += (size_t)NN * 4;
    int* rowptr  = (int*)p;   p += (size_t)(NN + 1) * 4;
    int* cursor  = (int*)p;   p += (size_t)NN * 4;
    int* colsrc  = (int*)p;   p += (size_t)NE * 4;

    hipMemsetAsync(cnt, 0, NN * 4, stream);
    hipMemsetAsync(cursor, 0, NN * 4, stream);
    hipMemsetAsync(degp, 0, NN * 4, stream);
    hipMemsetAsync(degn, 0, NN * 4, stream);

    k_tcn1<<<2500, 256, 0, stream>>>(x, tc1w1, tc1b1, tc1w2, tc1b2, out0);
    k_psi<<<(NN + 255) / 256, 256, 0, stream>>>(ndt, psiW1, psib1, psiW2, psib2, psib);
    k_deg<<<(NE + 255) / 256, 256, 0, stream>>>(ei, ea, cnt, degp, degn);
    k_dis<<<(NN + 255) / 256, 256, 0, stream>>>(degp, degn, disp, disn);
    k_scan<<<1, 1024, 0, stream>>>(cnt, rowptr);
    k_fill<<<(NE + 255) / 256, 256, 0, stream>>>(ei, ea, rowptr, cursor, disp, disn,
                                                 colsrc, normp, normn);

    dim3 ggrid((NN + BM - 1) / BM, FF / BN);
    // positive hops (psi-weighted accumulation fused into aggregation)
    k_gemm<<<ggrid, 256, 0, stream>>>(out0, Wpos, bufB, NN);
    k_agg<<<NN, 640, 0, stream>>>(bufB, rowptr, colsrc, normp, disp, bpos, bufA, accb, psib, 0);
    k_gemm<<<ggrid, 256, 0, stream>>>(bufA, Wpos, bufB, NN);
    k_agg<<<NN, 640, 0, stream>>>(bufB, rowptr, colsrc, normp, disp, bpos, bufA, accb, psib, 1);
    k_gemm<<<ggrid, 256, 0, stream>>>(bufA, Wpos, bufB, NN);
    k_agg<<<NN, 640, 0, stream>>>(bufB, rowptr, colsrc, normp, disp, bpos, bufA, accb, psib, 2);
    // negative branch (h3 in bufA is dead after hop-2 acc update -> reuse)
    k_gemm<<<ggrid, 256, 0, stream>>>(out0, Wneg, bufB, NN);
    k_agg<<<NN, 640, 0, stream>>>(bufB, rowptr, colsrc, normn, disn, bneg, bufA,
                                  (float*)nullptr, psib, 0);
    // channel mix + relu
    k_greto<<<NN, 640, 0, stream>>>(accb, bufA, greW, greb, bufB);
    // final gated TCN
    k_tcn2<<<2500, 256, 0, stream>>>(bufB, tc2w1, tc2b1, tc2w2, tc2b2, out);
}

// Round 6
// 1504.013 us; speedup vs baseline: 1.0068x; 1.0068x over previous
//
#include <hip/hip_runtime.h>
#include <math.h>

#define NN   10000   // nodes
#define NE   160000  // edges
#define CCH  64      // in/out channels
#define TIN  12      // input time steps
#define HCH  64      // hidden channels
#define TSP  10      // T - 2
#define FF   640     // H * TSP
#define TOUT 8       // TSP - 2

// ---------------- weight transpose: wt[k][cin][cout] = w[cout][cin][k] ------
// 4 sections: tc1_w1, tc1_w2, tc2_w1, tc2_w2 (each 64*64*3 = 12288 floats)
__global__ void k_wt(const float* __restrict__ s0, const float* __restrict__ s1,
                     const float* __restrict__ s2, const float* __restrict__ s3,
                     float* __restrict__ dst)
{
    int e = blockIdx.x * 256 + threadIdx.x;
    if (e >= 4 * 12288) return;
    int s = e / 12288, r = e % 12288;
    const float* src = (s == 0) ? s0 : (s == 1) ? s1 : (s == 2) ? s2 : s3;
    int o = r & 63;            // out channel (lane-coalesced in dst)
    int i = (r >> 6) & 63;     // in channel
    int k = r >> 12;           // tap
    dst[e] = src[(o * 64 + i) * 3 + k];
}

// ---------------- TCN1: x[N,64,12] -> out[N, 64*10] (f = h*10 + t) ----------
__global__ __launch_bounds__(256) void k_tcn1(const float* __restrict__ x,
                       const float* __restrict__ wt,   // wA=[3][64][64], wB at +12288
                       const float* __restrict__ b1, const float* __restrict__ b2,
                       float* __restrict__ out)
{
    __shared__ float xs[4][CCH * TIN];   // 12 KB
    const float* wA = wt;
    const float* wB = wt + 12288;
    int node0 = blockIdx.x * 4;
    for (int i = threadIdx.x; i < 4 * CCH * TIN; i += 256) {
        int nn = i / (CCH * TIN), off = i % (CCH * TIN);
        int g = node0 + nn;
        xs[nn][off] = (g < NN) ? x[(size_t)g * CCH * TIN + off] : 0.f;
    }
    __syncthreads();
    int ln = threadIdx.x >> 6, h = threadIdx.x & 63;
    int node = node0 + ln;
    if (node >= NN) return;
    float s1[TSP], s2[TSP];
    float bb1 = b1[h], bb2 = b2[h];
#pragma unroll
    for (int t = 0; t < TSP; ++t) { s1[t] = bb1; s2[t] = bb2; }
    for (int c = 0; c < CCH; ++c) {
        int wi = c * 64 + h;                  // coalesced across lanes
        float a0 = wA[wi], a1 = wA[4096 + wi], a2 = wA[8192 + wi];
        float g0 = wB[wi], g1 = wB[4096 + wi], g2 = wB[8192 + wi];
        const float* xr = &xs[ln][c * TIN];   // 48B-aligned
        float4 q0 = *(const float4*)&xr[0];
        float4 q1 = *(const float4*)&xr[4];
        float4 q2 = *(const float4*)&xr[8];
        float v[TIN] = {q0.x,q0.y,q0.z,q0.w, q1.x,q1.y,q1.z,q1.w,
                        q2.x,q2.y,q2.z,q2.w};
#pragma unroll
        for (int t = 0; t < TSP; ++t) {
            s1[t] += a0 * v[t] + a1 * v[t + 1] + a2 * v[t + 2];
            s2[t] += g0 * v[t] + g1 * v[t + 1] + g2 * v[t + 2];
        }
    }
#pragma unroll
    for (int t = 0; t < TSP; ++t) {
        float e = __expf(2.f * s1[t]);
        float th = 1.f - 2.f / (e + 1.f);
        float sg = 1.f / (1.f + __expf(-s2[t]));
        out[(size_t)node * FF + h * TSP + t] = th * sg;
    }
}

// ---------------- psi MLP: ND[N,3] -> psi[N,3] ------------------------------
__global__ void k_psi(const float* __restrict__ ND, const float* __restrict__ W1,
                      const float* __restrict__ b1, const float* __restrict__ W2,
                      const float* __restrict__ b2, float* __restrict__ psi)
{
    int n = blockIdx.x * blockDim.x + threadIdx.x;
    if (n >= NN) return;
    float d0 = ND[n * 3], d1 = ND[n * 3 + 1], d2 = ND[n * 3 + 2];
    float o0 = b2[0], o1 = b2[1], o2 = b2[2];
    for (int j = 0; j < 64; ++j) {
        float hv = d0 * W1[j] + d1 * W1[64 + j] + d2 * W1[128 + j] + b1[j];
        hv = fmaxf(hv, 0.f);
        o0 += hv * W2[j * 3 + 0];
        o1 += hv * W2[j * 3 + 1];
        o2 += hv * W2[j * 3 + 2];
    }
    psi[n * 3 + 0] = o0; psi[n * 3 + 1] = o1; psi[n * 3 + 2] = o2;
}

// ---------------- degree / counts -------------------------------------------
__global__ void k_deg(const int* __restrict__ ei, const float* __restrict__ ea,
                      int* __restrict__ cnt, float* __restrict__ degp, float* __restrict__ degn)
{
    int e = blockIdx.x * blockDim.x + threadIdx.x;
    if (e >= NE) return;
    int d = ei[NE + e];
    atomicAdd(&cnt[d], 1);
    atomicAdd(&degp[d], ea[e * 2 + 0] + 1.f);
    atomicAdd(&degn[d], ea[e * 2 + 1] + 1.f);
}

__global__ void k_dis(const float* __restrict__ degp, const float* __restrict__ degn,
                      float* __restrict__ disp, float* __restrict__ disn)
{
    int n = blockIdx.x * blockDim.x + threadIdx.x;
    if (n >= NN) return;
    disp[n] = 1.f / sqrtf(degp[n] + 1.f);   // +1: self loop weight
    disn[n] = 1.f / sqrtf(degn[n] + 1.f);
}

// ---------------- exclusive scan of counts -> rowptr ------------------------
__global__ __launch_bounds__(1024) void k_scan(const int* __restrict__ cnt, int* __restrict__ rowptr)
{
    __shared__ int buf[1024];
    __shared__ int carry;
    if (threadIdx.x == 0) carry = 0;
    __syncthreads();
    for (int base = 0; base < NN; base += 1024) {
        int i = base + threadIdx.x;
        int v = (i < NN) ? cnt[i] : 0;
        buf[threadIdx.x] = v;
        __syncthreads();
        for (int off = 1; off < 1024; off <<= 1) {
            int t = (threadIdx.x >= (unsigned)off) ? buf[threadIdx.x - off] : 0;
            __syncthreads();
            buf[threadIdx.x] += t;
            __syncthreads();
        }
        if (i < NN) rowptr[i] = carry + buf[threadIdx.x] - v;
        __syncthreads();
        if (threadIdx.x == 0) carry += buf[1023];
        __syncthreads();
    }
    if (threadIdx.x == 0) rowptr[NN] = carry;
}

// ---------------- CSR fill ---------------------------------------------------
__global__ void k_fill(const int* __restrict__ ei, const float* __restrict__ ea,
                       const int* __restrict__ rowptr, int* __restrict__ cursor,
                       const float* __restrict__ disp, const float* __restrict__ disn,
                       int* __restrict__ colsrc, float* __restrict__ normp, float* __restrict__ normn)
{
    int e = blockIdx.x * blockDim.x + threadIdx.x;
    if (e >= NE) return;
    int s = ei[e], d = ei[NE + e];
    int slot = atomicAdd(&cursor[d], 1);
    int idx = rowptr[d] + slot;
    colsrc[idx] = s;
    normp[idx] = disp[s] * (ea[e * 2 + 0] + 1.f) * disp[d];
    normn[idx] = disn[s] * (ea[e * 2 + 1] + 1.f) * disn[d];
}

// ---------------- f32 GEMM: C[M,640] = A[M,640] @ B[640,640] ----------------
// 128 threads, BM=128 x BN=64 tile, 8x8 micro-tile, BK=16
#define BM 128
#define BN 64
#define BK 16
__global__ __launch_bounds__(128) void k_gemm(const float* __restrict__ A,
                                              const float* __restrict__ B,
                                              float* __restrict__ Cm, int M)
{
    __shared__ float As[BK][BM];   // transposed: As[k][r]
    __shared__ float Bs[BK][BN];
    int tid = threadIdx.x;          // 0..127
    int row0 = blockIdx.x * BM;
    int col0 = blockIdx.y * BN;
    int tx = tid & 7;               // 0..7  (col group of 8)
    int ty = tid >> 3;              // 0..15 (row group of 8)
    float acc[8][8] = {};
    int bk = tid >> 3;              // 0..15
    int bc = (tid & 7) * 8;         // 0..56
    for (int k0 = 0; k0 < FF; k0 += BK) {
        int grow = row0 + tid;
        float4 a0v = {0,0,0,0}, a1v = {0,0,0,0}, a2v = {0,0,0,0}, a3v = {0,0,0,0};
        if (grow < M) {
            const float* ap = &A[(size_t)grow * FF + k0];
            a0v = *(const float4*)&ap[0];
            a1v = *(const float4*)&ap[4];
            a2v = *(const float4*)&ap[8];
            a3v = *(const float4*)&ap[12];
        }
        const float* bp = &B[(size_t)(k0 + bk) * FF + col0 + bc];
        float4 b0v = *(const float4*)&bp[0];
        float4 b1v = *(const float4*)&bp[4];
        __syncthreads();
        As[ 0][tid] = a0v.x; As[ 1][tid] = a0v.y; As[ 2][tid] = a0v.z; As[ 3][tid] = a0v.w;
        As[ 4][tid] = a1v.x; As[ 5][tid] = a1v.y; As[ 6][tid] = a1v.z; As[ 7][tid] = a1v.w;
        As[ 8][tid] = a2v.x; As[ 9][tid] = a2v.y; As[10][tid] = a2v.z; As[11][tid] = a2v.w;
        As[12][tid] = a3v.x; As[13][tid] = a3v.y; As[14][tid] = a3v.z; As[15][tid] = a3v.w;
        *(float4*)&Bs[bk][bc]     = b0v;
        *(float4*)&Bs[bk][bc + 4] = b1v;
        __syncthreads();
#pragma unroll
        for (int k = 0; k < BK; ++k) {
            float4 ra0 = *(const float4*)&As[k][ty * 8];
            float4 ra1 = *(const float4*)&As[k][ty * 8 + 4];
            float4 rb0 = *(const float4*)&Bs[k][tx * 8];
            float4 rb1 = *(const float4*)&Bs[k][tx * 8 + 4];
            float av[8] = {ra0.x,ra0.y,ra0.z,ra0.w, ra1.x,ra1.y,ra1.z,ra1.w};
            float bv[8] = {rb0.x,rb0.y,rb0.z,rb0.w, rb1.x,rb1.y,rb1.z,rb1.w};
#pragma unroll
            for (int i = 0; i < 8; ++i)
#pragma unroll
                for (int j = 0; j < 8; ++j)
                    acc[i][j] += av[i] * bv[j];
        }
    }
#pragma unroll
    for (int i = 0; i < 8; ++i) {
        int r = row0 + ty * 8 + i;
        if (r < M) {
            float4 o0 = {acc[i][0], acc[i][1], acc[i][2], acc[i][3]};
            float4 o1 = {acc[i][4], acc[i][5], acc[i][6], acc[i][7]};
            *(float4*)&Cm[(size_t)r * FF + col0 + tx * 8]     = o0;
            *(float4*)&Cm[(size_t)r * FF + col0 + tx * 8 + 4] = o1;
        }
    }
}

// ---------------- GCN aggregate: out[d] = relu(Anorm @ h + b); acc += psi*h --
__global__ void k_agg(const float* __restrict__ hsrc, const int* __restrict__ rowptr,
                      const int* __restrict__ colsrc, const float* __restrict__ enorm,
                      const float* __restrict__ dis, const float* __restrict__ bias,
                      float* __restrict__ hout, float* __restrict__ acc,
                      const float* __restrict__ psi, int hop)
{
    int d = blockIdx.x;
    int f = threadIdx.x;            // 640 threads
    float selfw = dis[d] * dis[d];
    float v = selfw * hsrc[(size_t)d * FF + f];
    int beg = rowptr[d], end = rowptr[d + 1];
    for (int idx = beg; idx < end; ++idx) {
        int s = colsrc[idx];
        float w = enorm[idx];
        v += w * hsrc[(size_t)s * FF + f];
    }
    v += bias[f];
    v = fmaxf(v, 0.f);
    hout[(size_t)d * FF + f] = v;
    if (acc) {
        float pv = psi[d * 3 + hop];
        if (hop == 0) acc[(size_t)d * FF + f] = pv * v;
        else          acc[(size_t)d * FF + f] += pv * v;
    }
}

// ---------------- GReTo mix: out[n,d,t] = relu(sum_c cat[n,c,t]*gW[c,d]+gb) --
__global__ void k_greto(const float* __restrict__ accb, const float* __restrict__ neg,
                        const float* __restrict__ gW, const float* __restrict__ gb,
                        float* __restrict__ out)
{
    __shared__ float sa[FF], sn[FF];
    int n = blockIdx.x;
    for (int i = threadIdx.x; i < FF; i += 640) {
        sa[i] = accb[(size_t)n * FF + i];
        sn[i] = neg[(size_t)n * FF + i];
    }
    __syncthreads();
    int t = threadIdx.x >> 6;       // 0..9, wave-uniform
    int d = threadIdx.x & 63;       // coalesced over gW
    float v = gb[d];
    for (int c = 0; c < HCH; ++c) {
        v += sa[c * TSP + t] * gW[c * HCH + d];
        v += sn[c * TSP + t] * gW[(HCH + c) * HCH + d];
    }
    out[(size_t)n * FF + d * TSP + t] = fmaxf(v, 0.f);
}

// ---------------- TCN2: g[N,64,10] -> out[N,64,8] ---------------------------
__global__ __launch_bounds__(256) void k_tcn2(const float* __restrict__ g,
                       const float* __restrict__ wt,   // wA at +24576, wB at +36864
                       const float* __restrict__ b1, const float* __restrict__ b2,
                       float* __restrict__ out)
{
    __shared__ float xs[4][HCH * 12];   // padded rows of 12 for float4 reads
    const float* wA = wt + 24576;
    const float* wB = wt + 36864;
    int node0 = blockIdx.x * 4;
    for (int i = threadIdx.x; i < 4 * HCH * TSP; i += 256) {
        int nn = i / (HCH * TSP), off = i % (HCH * TSP);
        int h = off / TSP, t = off % TSP;
        int gg = node0 + nn;
        xs[nn][h * 12 + t] = (gg < NN) ? g[(size_t)gg * FF + off] : 0.f;
    }
    __syncthreads();
    int ln = threadIdx.x >> 6, c = threadIdx.x & 63;
    int node = node0 + ln;
    if (node >= NN) return;
    float s1[TOUT], s2[TOUT];
    float bb1 = b1[c], bb2 = b2[c];
#pragma unroll
    for (int t = 0; t < TOUT; ++t) { s1[t] = bb1; s2[t] = bb2; }
    for (int h = 0; h < HCH; ++h) {
        int wi = h * 64 + c;                  // coalesced across lanes
        float a0 = wA[wi], a1 = wA[4096 + wi], a2 = wA[8192 + wi];
        float g0 = wB[wi], g1 = wB[4096 + wi], g2 = wB[8192 + wi];
        const float* xr = &xs[ln][h * 12];    // 48B-aligned
        float4 q0 = *(const float4*)&xr[0];
        float4 q1 = *(const float4*)&xr[4];
        float4 q2 = *(const float4*)&xr[8];
        float v[12] = {q0.x,q0.y,q0.z,q0.w, q1.x,q1.y,q1.z,q1.w,
                       q2.x,q2.y,q2.z,q2.w};
#pragma unroll
        for (int t = 0; t < TOUT; ++t) {
            s1[t] += a0 * v[t] + a1 * v[t + 1] + a2 * v[t + 2];
            s2[t] += g0 * v[t] + g1 * v[t + 1] + g2 * v[t + 2];
        }
    }
#pragma unroll
    for (int t = 0; t < TOUT; ++t) {
        float e = __expf(2.f * s1[t]);
        float th = 1.f - 2.f / (e + 1.f);
        float sg = 1.f / (1.f + __expf(-s2[t]));
        out[(size_t)node * (CCH * TOUT) + c * TOUT + t] = th * sg;
    }
}

extern "C" void kernel_launch(void* const* d_in, const int* in_sizes, int n_in,
                              void* d_out, int out_size, void* d_ws, size_t ws_size,
                              hipStream_t stream)
{
    const float* x     = (const float*)d_in[0];
    const int*   ei    = (const int*)  d_in[1];
    const float* ea    = (const float*)d_in[2];
    const float* ndt   = (const float*)d_in[3];
    const float* tc1w1 = (const float*)d_in[4];
    const float* tc1b1 = (const float*)d_in[5];
    const float* tc1w2 = (const float*)d_in[6];
    const float* tc1b2 = (const float*)d_in[7];
    const float* Wpos  = (const float*)d_in[8];
    const float* bpos  = (const float*)d_in[9];
    const float* Wneg  = (const float*)d_in[10];
    const float* bneg  = (const float*)d_in[11];
    const float* greW  = (const float*)d_in[12];
    const float* greb  = (const float*)d_in[13];
    const float* psiW1 = (const float*)d_in[14];
    const float* psib1 = (const float*)d_in[15];
    const float* psiW2 = (const float*)d_in[16];
    const float* psib2 = (const float*)d_in[17];
    const float* tc2w1 = (const float*)d_in[18];
    const float* tc2b1 = (const float*)d_in[19];
    const float* tc2w2 = (const float*)d_in[20];
    const float* tc2b2 = (const float*)d_in[21];
    float* out = (float*)d_out;

    char* p = (char*)d_ws;
    float* out0  = (float*)p; p += (size_t)NN * FF * 4;
    float* bufB  = (float*)p; p += (size_t)NN * FF * 4;
    float* bufA  = (float*)p; p += (size_t)NN * FF * 4;
    float* accb  = (float*)p; p += (size_t)NN * FF * 4;
    float* psib  = (float*)p; p += (size_t)NN * 3 * 4;
    float* degp  = (float*)p; p += (size_t)NN * 4;
    float* degn  = (float*)p; p += (size_t)NN * 4;
    float* disp  = (float*)p; p += (size_t)NN * 4;
    float* disn  = (float*)p; p += (size_t)NN * 4;
    float* normp = (float*)p; p += (size_t)NE * 4;
    float* normn = (float*)p; p += (size_t)NE * 4;
    int* cnt     = (int*)p;   p += (size_t)NN * 4;
    int* rowptr  = (int*)p;   p += (size_t)(NN + 1) * 4;
    int* cursor  = (int*)p;   p += (size_t)NN * 4;
    int* colsrc  = (int*)p;   p += (size_t)NE * 4;
    float* wt    = (float*)p; p += (size_t)4 * 12288 * 4;   // transposed TCN weights

    (void)hipMemsetAsync(cnt, 0, NN * 4, stream);
    (void)hipMemsetAsync(cursor, 0, NN * 4, stream);
    (void)hipMemsetAsync(degp, 0, NN * 4, stream);
    (void)hipMemsetAsync(degn, 0, NN * 4, stream);

    k_wt<<<(4 * 12288 + 255) / 256, 256, 0, stream>>>(tc1w1, tc1w2, tc2w1, tc2w2, wt);
    k_tcn1<<<2500, 256, 0, stream>>>(x, wt, tc1b1, tc1b2, out0);
    k_psi<<<(NN + 255) / 256, 256, 0, stream>>>(ndt, psiW1, psib1, psiW2, psib2, psib);
    k_deg<<<(NE + 255) / 256, 256, 0, stream>>>(ei, ea, cnt, degp, degn);
    k_dis<<<(NN + 255) / 256, 256, 0, stream>>>(degp, degn, disp, disn);
    k_scan<<<1, 1024, 0, stream>>>(cnt, rowptr);
    k_fill<<<(NE + 255) / 256, 256, 0, stream>>>(ei, ea, rowptr, cursor, disp, disn,
                                                 colsrc, normp, normn);

    dim3 ggrid((NN + BM - 1) / BM, FF / BN);
    // positive hops (psi-weighted accumulation fused into aggregation)
    k_gemm<<<ggrid, 128, 0, stream>>>(out0, Wpos, bufB, NN);
    k_agg<<<NN, 640, 0, stream>>>(bufB, rowptr, colsrc, normp, disp, bpos, bufA, accb, psib, 0);
    k_gemm<<<ggrid, 128, 0, stream>>>(bufA, Wpos, bufB, NN);
    k_agg<<<NN, 640, 0, stream>>>(bufB, rowptr, colsrc, normp, disp, bpos, bufA, accb, psib, 1);
    k_gemm<<<ggrid, 128, 0, stream>>>(bufA, Wpos, bufB, NN);
    k_agg<<<NN, 640, 0, stream>>>(bufB, rowptr, colsrc, normp, disp, bpos, bufA, accb, psib, 2);
    // negative branch (h3 in bufA is dead after hop-2 acc update -> reuse)
    k_gemm<<<ggrid, 128, 0, stream>>>(out0, Wneg, bufB, NN);
    k_agg<<<NN, 640, 0, stream>>>(bufB, rowptr, colsrc, normn, disn, bneg, bufA,
                                  (float*)nullptr, psib, 0);
    // channel mix + relu
    k_greto<<<NN, 640, 0, stream>>>(accb, bufA, greW, greb, bufB);
    // final gated TCN
    k_tcn2<<<2500, 256, 0, stream>>>(bufB, wt, tc2b1, tc2b2, out);
}

// Round 7
// 932.906 us; speedup vs baseline: 1.6232x; 1.6122x over previous
//
#include <hip/hip_runtime.h>
#include <math.h>

#define NN   10000   // nodes
#define NE   160000  // edges
#define CCH  64      // in/out channels
#define TIN  12      // input time steps
#define HCH  64      // hidden channels
#define TSP  10      // T - 2
#define FF   640     // H * TSP
#define TOUT 8       // TSP - 2

typedef _Float16 f16;
typedef _Float16 f16x8 __attribute__((ext_vector_type(8)));
typedef float f32x4 __attribute__((ext_vector_type(4)));

// ---------------- weight transpose: wt[k][cin][cout] = w[cout][cin][k] ------
__global__ void k_wt(const float* __restrict__ s0, const float* __restrict__ s1,
                     const float* __restrict__ s2, const float* __restrict__ s3,
                     float* __restrict__ dst)
{
    int e = blockIdx.x * 256 + threadIdx.x;
    if (e >= 4 * 12288) return;
    int s = e / 12288, r = e % 12288;
    const float* src = (s == 0) ? s0 : (s == 1) ? s1 : (s == 2) ? s2 : s3;
    int o = r & 63;
    int i = (r >> 6) & 63;
    int k = r >> 12;
    dst[e] = src[(o * 64 + i) * 3 + k];
}

// ---------------- TCN1: x[N,64,12] -> out f16 [N, 64*10] --------------------
__global__ __launch_bounds__(256) void k_tcn1(const float* __restrict__ x,
                       const float* __restrict__ wt,
                       const float* __restrict__ b1, const float* __restrict__ b2,
                       f16* __restrict__ out)
{
    __shared__ float xs[4][CCH * TIN];
    const float* wA = wt;
    const float* wB = wt + 12288;
    int node0 = blockIdx.x * 4;
    for (int i = threadIdx.x; i < 4 * CCH * TIN; i += 256) {
        int nn = i / (CCH * TIN), off = i % (CCH * TIN);
        int g = node0 + nn;
        xs[nn][off] = (g < NN) ? x[(size_t)g * CCH * TIN + off] : 0.f;
    }
    __syncthreads();
    int ln = threadIdx.x >> 6, h = threadIdx.x & 63;
    int node = node0 + ln;
    if (node >= NN) return;
    float s1[TSP], s2[TSP];
    float bb1 = b1[h], bb2 = b2[h];
#pragma unroll
    for (int t = 0; t < TSP; ++t) { s1[t] = bb1; s2[t] = bb2; }
    for (int c = 0; c < CCH; ++c) {
        int wi = c * 64 + h;
        float a0 = wA[wi], a1 = wA[4096 + wi], a2 = wA[8192 + wi];
        float g0 = wB[wi], g1 = wB[4096 + wi], g2 = wB[8192 + wi];
        const float* xr = &xs[ln][c * TIN];
        float4 q0 = *(const float4*)&xr[0];
        float4 q1 = *(const float4*)&xr[4];
        float4 q2 = *(const float4*)&xr[8];
        float v[TIN] = {q0.x,q0.y,q0.z,q0.w, q1.x,q1.y,q1.z,q1.w,
                        q2.x,q2.y,q2.z,q2.w};
#pragma unroll
        for (int t = 0; t < TSP; ++t) {
            s1[t] += a0 * v[t] + a1 * v[t + 1] + a2 * v[t + 2];
            s2[t] += g0 * v[t] + g1 * v[t + 1] + g2 * v[t + 2];
        }
    }
#pragma unroll
    for (int t = 0; t < TSP; ++t) {
        float e = __expf(2.f * s1[t]);
        float th = 1.f - 2.f / (e + 1.f);
        float sg = 1.f / (1.f + __expf(-s2[t]));
        out[(size_t)node * FF + h * TSP + t] = (f16)(th * sg);
    }
}

// ---------------- psi MLP ---------------------------------------------------
__global__ void k_psi(const float* __restrict__ ND, const float* __restrict__ W1,
                      const float* __restrict__ b1, const float* __restrict__ W2,
                      const float* __restrict__ b2, float* __restrict__ psi)
{
    int n = blockIdx.x * blockDim.x + threadIdx.x;
    if (n >= NN) return;
    float d0 = ND[n * 3], d1 = ND[n * 3 + 1], d2 = ND[n * 3 + 2];
    float o0 = b2[0], o1 = b2[1], o2 = b2[2];
    for (int j = 0; j < 64; ++j) {
        float hv = d0 * W1[j] + d1 * W1[64 + j] + d2 * W1[128 + j] + b1[j];
        hv = fmaxf(hv, 0.f);
        o0 += hv * W2[j * 3 + 0];
        o1 += hv * W2[j * 3 + 1];
        o2 += hv * W2[j * 3 + 2];
    }
    psi[n * 3 + 0] = o0; psi[n * 3 + 1] = o1; psi[n * 3 + 2] = o2;
}

// ---------------- degree / counts -------------------------------------------
__global__ void k_deg(const int* __restrict__ ei, const float* __restrict__ ea,
                      int* __restrict__ cnt, float* __restrict__ degp, float* __restrict__ degn)
{
    int e = blockIdx.x * blockDim.x + threadIdx.x;
    if (e >= NE) return;
    int d = ei[NE + e];
    atomicAdd(&cnt[d], 1);
    atomicAdd(&degp[d], ea[e * 2 + 0] + 1.f);
    atomicAdd(&degn[d], ea[e * 2 + 1] + 1.f);
}

__global__ void k_dis(const float* __restrict__ degp, const float* __restrict__ degn,
                      float* __restrict__ disp, float* __restrict__ disn)
{
    int n = blockIdx.x * blockDim.x + threadIdx.x;
    if (n >= NN) return;
    disp[n] = 1.f / sqrtf(degp[n] + 1.f);
    disn[n] = 1.f / sqrtf(degn[n] + 1.f);
}

// ---------------- exclusive scan --------------------------------------------
__global__ __launch_bounds__(1024) void k_scan(const int* __restrict__ cnt, int* __restrict__ rowptr)
{
    __shared__ int buf[1024];
    __shared__ int carry;
    if (threadIdx.x == 0) carry = 0;
    __syncthreads();
    for (int base = 0; base < NN; base += 1024) {
        int i = base + threadIdx.x;
        int v = (i < NN) ? cnt[i] : 0;
        buf[threadIdx.x] = v;
        __syncthreads();
        for (int off = 1; off < 1024; off <<= 1) {
            int t = (threadIdx.x >= (unsigned)off) ? buf[threadIdx.x - off] : 0;
            __syncthreads();
            buf[threadIdx.x] += t;
            __syncthreads();
        }
        if (i < NN) rowptr[i] = carry + buf[threadIdx.x] - v;
        __syncthreads();
        if (threadIdx.x == 0) carry += buf[1023];
        __syncthreads();
    }
    if (threadIdx.x == 0) rowptr[NN] = carry;
}

// ---------------- CSR fill ---------------------------------------------------
__global__ void k_fill(const int* __restrict__ ei, const float* __restrict__ ea,
                       const int* __restrict__ rowptr, int* __restrict__ cursor,
                       const float* __restrict__ disp, const float* __restrict__ disn,
                       int* __restrict__ colsrc, float* __restrict__ normp, float* __restrict__ normn)
{
    int e = blockIdx.x * blockDim.x + threadIdx.x;
    if (e >= NE) return;
    int s = ei[e], d = ei[NE + e];
    int slot = atomicAdd(&cursor[d], 1);
    int idx = rowptr[d] + slot;
    colsrc[idx] = s;
    normp[idx] = disp[s] * (ea[e * 2 + 0] + 1.f) * disp[d];
    normn[idx] = disn[s] * (ea[e * 2 + 1] + 1.f) * disn[d];
}

// ---------------- W transpose+cast: Wt[n][k] = (f16)W[k][n] -----------------
__global__ __launch_bounds__(256) void k_wsplit(const float* __restrict__ W, f16* __restrict__ Wt)
{
    __shared__ float t[32][33];
    int bx = blockIdx.x * 32;   // k block
    int by = blockIdx.y * 32;   // n block
    int tx = threadIdx.x & 31, ty = threadIdx.x >> 5;  // ty 0..7
#pragma unroll
    for (int j = 0; j < 4; ++j)
        t[ty + j * 8][tx] = W[(size_t)(bx + ty + j * 8) * 640 + by + tx];
    __syncthreads();
#pragma unroll
    for (int j = 0; j < 4; ++j)
        Wt[(size_t)(by + ty + j * 8) * 640 + bx + tx] = (f16)t[tx][ty + j * 8];
}

// ---------------- f16 MFMA GEMM: C[M,640] = A[M,640] @ Bt^T -----------------
// A [M][640] f16 row-major; Bt [640][640] f16 with Bt[n][k] = B[k][n]
// 256 threads = 4 waves (2x2), tile 128x128, 16x16x32 MFMA
__global__ __launch_bounds__(256) void k_gemm16(const f16* __restrict__ A,
                                                const f16* __restrict__ Bt,
                                                float* __restrict__ C, int M)
{
    __shared__ f16 As[128][40];   // rows padded 32->40 f16 (80B): 2-way bank alias only
    __shared__ f16 Bs[128][40];
    int tid = threadIdx.x;
    int row0 = blockIdx.x * 128;
    int col0 = blockIdx.y * 128;
    int w = tid >> 6, l = tid & 63;
    int wr = (w >> 1) * 64;       // wave row offset
    int wc = (w & 1) * 64;        // wave col offset
    int lrow = l & 15;
    int lk = (l >> 4) * 8;
    int srow = tid >> 2;          // 0..63
    int sseg = (tid & 3) * 8;     // 0,8,16,24

    f32x4 acc[4][4];
#pragma unroll
    for (int m = 0; m < 4; ++m)
#pragma unroll
        for (int n = 0; n < 4; ++n)
            acc[m][n] = (f32x4){0.f, 0.f, 0.f, 0.f};

    for (int k0 = 0; k0 < FF; k0 += 32) {
        f16x8 a0 = {}, a1 = {};
        int r0 = row0 + srow, r1 = row0 + srow + 64;
        if (r0 < M) a0 = *(const f16x8*)&A[(size_t)r0 * FF + k0 + sseg];
        if (r1 < M) a1 = *(const f16x8*)&A[(size_t)r1 * FF + k0 + sseg];
        f16x8 b0 = *(const f16x8*)&Bt[(size_t)(col0 + srow) * FF + k0 + sseg];
        f16x8 b1 = *(const f16x8*)&Bt[(size_t)(col0 + srow + 64) * FF + k0 + sseg];
        __syncthreads();
        *(f16x8*)&As[srow][sseg]      = a0;
        *(f16x8*)&As[srow + 64][sseg] = a1;
        *(f16x8*)&Bs[srow][sseg]      = b0;
        *(f16x8*)&Bs[srow + 64][sseg] = b1;
        __syncthreads();
        f16x8 af[4], bf[4];
#pragma unroll
        for (int m = 0; m < 4; ++m)
            af[m] = *(const f16x8*)&As[wr + m * 16 + lrow][lk];
#pragma unroll
        for (int n = 0; n < 4; ++n)
            bf[n] = *(const f16x8*)&Bs[wc + n * 16 + lrow][lk];
#pragma unroll
        for (int m = 0; m < 4; ++m)
#pragma unroll
            for (int n = 0; n < 4; ++n)
                acc[m][n] = __builtin_amdgcn_mfma_f32_16x16x32_f16(af[m], bf[n], acc[m][n], 0, 0, 0);
    }
    int orow = (l >> 4) * 4;
#pragma unroll
    for (int m = 0; m < 4; ++m) {
#pragma unroll
        for (int r = 0; r < 4; ++r) {
            int rr = row0 + wr + m * 16 + orow + r;
            if (rr < M) {
#pragma unroll
                for (int n = 0; n < 4; ++n)
                    C[(size_t)rr * FF + col0 + wc + n * 16 + lrow] = acc[m][n][r];
            }
        }
    }
}

// ---------------- GCN aggregate (f32 in from GEMM, f16 out) -----------------
__global__ void k_agg(const float* __restrict__ hsrc, const int* __restrict__ rowptr,
                      const int* __restrict__ colsrc, const float* __restrict__ enorm,
                      const float* __restrict__ dis, const float* __restrict__ bias,
                      f16* __restrict__ hout, float* __restrict__ acc,
                      const float* __restrict__ psi, int hop)
{
    int d = blockIdx.x;
    int f = threadIdx.x;            // 640 threads
    float selfw = dis[d] * dis[d];
    float v = selfw * hsrc[(size_t)d * FF + f];
    int beg = rowptr[d], end = rowptr[d + 1];
    for (int idx = beg; idx < end; ++idx) {
        int s = colsrc[idx];
        float w = enorm[idx];
        v += w * hsrc[(size_t)s * FF + f];
    }
    v += bias[f];
    v = fmaxf(v, 0.f);
    hout[(size_t)d * FF + f] = (f16)v;
    if (acc) {
        float pv = psi[d * 3 + hop];
        if (hop == 0) acc[(size_t)d * FF + f] = pv * v;
        else          acc[(size_t)d * FF + f] += pv * v;
    }
}

// ---------------- GReTo mix -------------------------------------------------
__global__ void k_greto(const float* __restrict__ accb, const f16* __restrict__ neg,
                        const float* __restrict__ gW, const float* __restrict__ gb,
                        float* __restrict__ out)
{
    __shared__ float sa[FF], sn[FF];
    int n = blockIdx.x;
    for (int i = threadIdx.x; i < FF; i += 640) {
        sa[i] = accb[(size_t)n * FF + i];
        sn[i] = (float)neg[(size_t)n * FF + i];
    }
    __syncthreads();
    int t = threadIdx.x >> 6;
    int d = threadIdx.x & 63;
    float v = gb[d];
    for (int c = 0; c < HCH; ++c) {
        v += sa[c * TSP + t] * gW[c * HCH + d];
        v += sn[c * TSP + t] * gW[(HCH + c) * HCH + d];
    }
    out[(size_t)n * FF + d * TSP + t] = fmaxf(v, 0.f);
}

// ---------------- TCN2 ------------------------------------------------------
__global__ __launch_bounds__(256) void k_tcn2(const float* __restrict__ g,
                       const float* __restrict__ wt,
                       const float* __restrict__ b1, const float* __restrict__ b2,
                       float* __restrict__ out)
{
    __shared__ float xs[4][HCH * 12];
    const float* wA = wt + 24576;
    const float* wB = wt + 36864;
    int node0 = blockIdx.x * 4;
    for (int i = threadIdx.x; i < 4 * HCH * TSP; i += 256) {
        int nn = i / (HCH * TSP), off = i % (HCH * TSP);
        int h = off / TSP, t = off % TSP;
        int gg = node0 + nn;
        xs[nn][h * 12 + t] = (gg < NN) ? g[(size_t)gg * FF + off] : 0.f;
    }
    __syncthreads();
    int ln = threadIdx.x >> 6, c = threadIdx.x & 63;
    int node = node0 + ln;
    if (node >= NN) return;
    float s1[TOUT], s2[TOUT];
    float bb1 = b1[c], bb2 = b2[c];
#pragma unroll
    for (int t = 0; t < TOUT; ++t) { s1[t] = bb1; s2[t] = bb2; }
    for (int h = 0; h < HCH; ++h) {
        int wi = h * 64 + c;
        float a0 = wA[wi], a1 = wA[4096 + wi], a2 = wA[8192 + wi];
        float g0 = wB[wi], g1 = wB[4096 + wi], g2 = wB[8192 + wi];
        const float* xr = &xs[ln][h * 12];
        float4 q0 = *(const float4*)&xr[0];
        float4 q1 = *(const float4*)&xr[4];
        float4 q2 = *(const float4*)&xr[8];
        float v[12] = {q0.x,q0.y,q0.z,q0.w, q1.x,q1.y,q1.z,q1.w,
                       q2.x,q2.y,q2.z,q2.w};
#pragma unroll
        for (int t = 0; t < TOUT; ++t) {
            s1[t] += a0 * v[t] + a1 * v[t + 1] + a2 * v[t + 2];
            s2[t] += g0 * v[t] + g1 * v[t + 1] + g2 * v[t + 2];
        }
    }
#pragma unroll
    for (int t = 0; t < TOUT; ++t) {
        float e = __expf(2.f * s1[t]);
        float th = 1.f - 2.f / (e + 1.f);
        float sg = 1.f / (1.f + __expf(-s2[t]));
        out[(size_t)node * (CCH * TOUT) + c * TOUT + t] = th * sg;
    }
}

extern "C" void kernel_launch(void* const* d_in, const int* in_sizes, int n_in,
                              void* d_out, int out_size, void* d_ws, size_t ws_size,
                              hipStream_t stream)
{
    const float* x     = (const float*)d_in[0];
    const int*   ei    = (const int*)  d_in[1];
    const float* ea    = (const float*)d_in[2];
    const float* ndt   = (const float*)d_in[3];
    const float* tc1w1 = (const float*)d_in[4];
    const float* tc1b1 = (const float*)d_in[5];
    const float* tc1w2 = (const float*)d_in[6];
    const float* tc1b2 = (const float*)d_in[7];
    const float* Wpos  = (const float*)d_in[8];
    const float* bpos  = (const float*)d_in[9];
    const float* Wneg  = (const float*)d_in[10];
    const float* bneg  = (const float*)d_in[11];
    const float* greW  = (const float*)d_in[12];
    const float* greb  = (const float*)d_in[13];
    const float* psiW1 = (const float*)d_in[14];
    const float* psib1 = (const float*)d_in[15];
    const float* psiW2 = (const float*)d_in[16];
    const float* psib2 = (const float*)d_in[17];
    const float* tc2w1 = (const float*)d_in[18];
    const float* tc2b1 = (const float*)d_in[19];
    const float* tc2w2 = (const float*)d_in[20];
    const float* tc2b2 = (const float*)d_in[21];
    float* out = (float*)d_out;

    char* p = (char*)d_ws;
    f16*   out0h = (f16*)p;   p += (size_t)NN * FF * 2;
    f16*   h16a  = (f16*)p;   p += (size_t)NN * FF * 2;
    f16*   h16b  = (f16*)p;   p += (size_t)NN * FF * 2;
    float* Cbuf  = (float*)p; p += (size_t)NN * FF * 4;
    float* accb  = (float*)p; p += (size_t)NN * FF * 4;
    f16*   Wtp   = (f16*)p;   p += (size_t)FF * FF * 2;
    f16*   Wtn   = (f16*)p;   p += (size_t)FF * FF * 2;
    float* psib  = (float*)p; p += (size_t)NN * 3 * 4;
    float* degp  = (float*)p; p += (size_t)NN * 4;
    float* degn  = (float*)p; p += (size_t)NN * 4;
    float* disp  = (float*)p; p += (size_t)NN * 4;
    float* disn  = (float*)p; p += (size_t)NN * 4;
    float* normp = (float*)p; p += (size_t)NE * 4;
    float* normn = (float*)p; p += (size_t)NE * 4;
    int* cnt     = (int*)p;   p += (size_t)NN * 4;
    int* rowptr  = (int*)p;   p += (size_t)(NN + 1) * 4;
    int* cursor  = (int*)p;   p += (size_t)NN * 4;
    int* colsrc  = (int*)p;   p += (size_t)NE * 4;
    float* wt    = (float*)p; p += (size_t)4 * 12288 * 4;

    (void)hipMemsetAsync(cnt, 0, NN * 4, stream);
    (void)hipMemsetAsync(cursor, 0, NN * 4, stream);
    (void)hipMemsetAsync(degp, 0, NN * 4, stream);
    (void)hipMemsetAsync(degn, 0, NN * 4, stream);

    k_wt<<<(4 * 12288 + 255) / 256, 256, 0, stream>>>(tc1w1, tc1w2, tc2w1, tc2w2, wt);
    k_tcn1<<<2500, 256, 0, stream>>>(x, wt, tc1b1, tc1b2, out0h);
    k_psi<<<(NN + 255) / 256, 256, 0, stream>>>(ndt, psiW1, psib1, psiW2, psib2, psib);
    k_deg<<<(NE + 255) / 256, 256, 0, stream>>>(ei, ea, cnt, degp, degn);
    k_dis<<<(NN + 255) / 256, 256, 0, stream>>>(degp, degn, disp, disn);
    k_scan<<<1, 1024, 0, stream>>>(cnt, rowptr);
    k_fill<<<(NE + 255) / 256, 256, 0, stream>>>(ei, ea, rowptr, cursor, disp, disn,
                                                 colsrc, normp, normn);
    dim3 wgrid(20, 20);
    k_wsplit<<<wgrid, 256, 0, stream>>>(Wpos, Wtp);
    k_wsplit<<<wgrid, 256, 0, stream>>>(Wneg, Wtn);

    dim3 ggrid((NN + 127) / 128, FF / 128);
    // positive hops
    k_gemm16<<<ggrid, 256, 0, stream>>>(out0h, Wtp, Cbuf, NN);
    k_agg<<<NN, 640, 0, stream>>>(Cbuf, rowptr, colsrc, normp, disp, bpos, h16a, accb, psib, 0);
    k_gemm16<<<ggrid, 256, 0, stream>>>(h16a, Wtp, Cbuf, NN);
    k_agg<<<NN, 640, 0, stream>>>(Cbuf, rowptr, colsrc, normp, disp, bpos, h16b, accb, psib, 1);
    k_gemm16<<<ggrid, 256, 0, stream>>>(h16b, Wtp, Cbuf, NN);
    k_agg<<<NN, 640, 0, stream>>>(Cbuf, rowptr, colsrc, normp, disp, bpos, h16a, accb, psib, 2);
    // negative branch (h16b dead after hop-2 gemm -> reuse for neg output)
    k_gemm16<<<ggrid, 256, 0, stream>>>(out0h, Wtn, Cbuf, NN);
    k_agg<<<NN, 640, 0, stream>>>(Cbuf, rowptr, colsrc, normn, disn, bneg, h16b,
                                  (float*)nullptr, psib, 0);
    // channel mix + relu (Cbuf free after last agg -> reuse as greto output)
    k_greto<<<NN, 640, 0, stream>>>(accb, h16b, greW, greb, Cbuf);
    // final gated TCN
    k_tcn2<<<2500, 256, 0, stream>>>(Cbuf, wt, tc2b1, tc2b2, out);
}

// Round 9
// 894.732 us; speedup vs baseline: 1.6924x; 1.0427x over previous
//
#include <hip/hip_runtime.h>
#include <math.h>

#define NN   10000   // nodes
#define NE   160000  // edges
#define CCH  64      // in/out channels
#define TIN  12      // input time steps
#define HCH  64      // hidden channels
#define TSP  10      // T - 2
#define FF   640     // H * TSP
#define TOUT 8       // TSP - 2

typedef _Float16 f16;
typedef _Float16 f16x8 __attribute__((ext_vector_type(8)));
typedef float f32x4 __attribute__((ext_vector_type(4)));

// ---------------- weight transpose: wt[k][cin][cout] = w[cout][cin][k] ------
__global__ void k_wt(const float* __restrict__ s0, const float* __restrict__ s1,
                     const float* __restrict__ s2, const float* __restrict__ s3,
                     float* __restrict__ dst)
{
    int e = blockIdx.x * 256 + threadIdx.x;
    if (e >= 4 * 12288) return;
    int s = e / 12288, r = e % 12288;
    const float* src = (s == 0) ? s0 : (s == 1) ? s1 : (s == 2) ? s2 : s3;
    int o = r & 63;
    int i = (r >> 6) & 63;
    int k = r >> 12;
    dst[e] = src[(o * 64 + i) * 3 + k];
}

// ---------------- TCN1: x[N,64,12] -> out f16 [N, 64*10] --------------------
__global__ __launch_bounds__(256) void k_tcn1(const float* __restrict__ x,
                       const float* __restrict__ wt,
                       const float* __restrict__ b1, const float* __restrict__ b2,
                       f16* __restrict__ out)
{
    __shared__ float xs[4][CCH * TIN];
    const float* wA = wt;
    const float* wB = wt + 12288;
    int node0 = blockIdx.x * 4;
    for (int i = threadIdx.x; i < 4 * CCH * TIN; i += 256) {
        int nn = i / (CCH * TIN), off = i % (CCH * TIN);
        int g = node0 + nn;
        xs[nn][off] = (g < NN) ? x[(size_t)g * CCH * TIN + off] : 0.f;
    }
    __syncthreads();
    int ln = threadIdx.x >> 6, h = threadIdx.x & 63;
    int node = node0 + ln;
    if (node >= NN) return;
    float s1[TSP], s2[TSP];
    float bb1 = b1[h], bb2 = b2[h];
#pragma unroll
    for (int t = 0; t < TSP; ++t) { s1[t] = bb1; s2[t] = bb2; }
    for (int c = 0; c < CCH; ++c) {
        int wi = c * 64 + h;
        float a0 = wA[wi], a1 = wA[4096 + wi], a2 = wA[8192 + wi];
        float g0 = wB[wi], g1 = wB[4096 + wi], g2 = wB[8192 + wi];
        const float* xr = &xs[ln][c * TIN];
        float4 q0 = *(const float4*)&xr[0];
        float4 q1 = *(const float4*)&xr[4];
        float4 q2 = *(const float4*)&xr[8];
        float v[TIN] = {q0.x,q0.y,q0.z,q0.w, q1.x,q1.y,q1.z,q1.w,
                        q2.x,q2.y,q2.z,q2.w};
#pragma unroll
        for (int t = 0; t < TSP; ++t) {
            s1[t] += a0 * v[t] + a1 * v[t + 1] + a2 * v[t + 2];
            s2[t] += g0 * v[t] + g1 * v[t + 1] + g2 * v[t + 2];
        }
    }
#pragma unroll
    for (int t = 0; t < TSP; ++t) {
        float e = __expf(2.f * s1[t]);
        float th = 1.f - 2.f / (e + 1.f);
        float sg = 1.f / (1.f + __expf(-s2[t]));
        out[(size_t)node * FF + h * TSP + t] = (f16)(th * sg);
    }
}

// ---------------- psi MLP ---------------------------------------------------
__global__ void k_psi(const float* __restrict__ ND, const float* __restrict__ W1,
                      const float* __restrict__ b1, const float* __restrict__ W2,
                      const float* __restrict__ b2, float* __restrict__ psi)
{
    int n = blockIdx.x * blockDim.x + threadIdx.x;
    if (n >= NN) return;
    float d0 = ND[n * 3], d1 = ND[n * 3 + 1], d2 = ND[n * 3 + 2];
    float o0 = b2[0], o1 = b2[1], o2 = b2[2];
    for (int j = 0; j < 64; ++j) {
        float hv = d0 * W1[j] + d1 * W1[64 + j] + d2 * W1[128 + j] + b1[j];
        hv = fmaxf(hv, 0.f);
        o0 += hv * W2[j * 3 + 0];
        o1 += hv * W2[j * 3 + 1];
        o2 += hv * W2[j * 3 + 2];
    }
    psi[n * 3 + 0] = o0; psi[n * 3 + 1] = o1; psi[n * 3 + 2] = o2;
}

// ---------------- degree / counts -------------------------------------------
__global__ void k_deg(const int* __restrict__ ei, const float* __restrict__ ea,
                      int* __restrict__ cnt, float* __restrict__ degp, float* __restrict__ degn)
{
    int e = blockIdx.x * blockDim.x + threadIdx.x;
    if (e >= NE) return;
    int d = ei[NE + e];
    atomicAdd(&cnt[d], 1);
    atomicAdd(&degp[d], ea[e * 2 + 0] + 1.f);
    atomicAdd(&degn[d], ea[e * 2 + 1] + 1.f);
}

__global__ void k_dis(const float* __restrict__ degp, const float* __restrict__ degn,
                      float* __restrict__ disp, float* __restrict__ disn)
{
    int n = blockIdx.x * blockDim.x + threadIdx.x;
    if (n >= NN) return;
    disp[n] = 1.f / sqrtf(degp[n] + 1.f);
    disn[n] = 1.f / sqrtf(degn[n] + 1.f);
}

// ---------------- exclusive scan --------------------------------------------
__global__ __launch_bounds__(1024) void k_scan(const int* __restrict__ cnt, int* __restrict__ rowptr)
{
    __shared__ int buf[1024];
    __shared__ int carry;
    if (threadIdx.x == 0) carry = 0;
    __syncthreads();
    for (int base = 0; base < NN; base += 1024) {
        int i = base + threadIdx.x;
        int v = (i < NN) ? cnt[i] : 0;
        buf[threadIdx.x] = v;
        __syncthreads();
        for (int off = 1; off < 1024; off <<= 1) {
            int t = (threadIdx.x >= (unsigned)off) ? buf[threadIdx.x - off] : 0;
            __syncthreads();
            buf[threadIdx.x] += t;
            __syncthreads();
        }
        if (i < NN) rowptr[i] = carry + buf[threadIdx.x] - v;
        __syncthreads();
        if (threadIdx.x == 0) carry += buf[1023];
        __syncthreads();
    }
    if (threadIdx.x == 0) rowptr[NN] = carry;
}

// ---------------- CSR fill ---------------------------------------------------
__global__ void k_fill(const int* __restrict__ ei, const float* __restrict__ ea,
                       const int* __restrict__ rowptr, int* __restrict__ cursor,
                       const float* __restrict__ disp, const float* __restrict__ disn,
                       int* __restrict__ colsrc, float* __restrict__ normp, float* __restrict__ normn)
{
    int e = blockIdx.x * blockDim.x + threadIdx.x;
    if (e >= NE) return;
    int s = ei[e], d = ei[NE + e];
    int slot = atomicAdd(&cursor[d], 1);
    int idx = rowptr[d] + slot;
    colsrc[idx] = s;
    normp[idx] = disp[s] * (ea[e * 2 + 0] + 1.f) * disp[d];
    normn[idx] = disn[s] * (ea[e * 2 + 1] + 1.f) * disn[d];
}

// ---------------- W transpose+cast: Wt[n][k] = (f16)W[k][n] -----------------
__global__ __launch_bounds__(256) void k_wsplit(const float* __restrict__ W, f16* __restrict__ Wt)
{
    __shared__ float t[32][33];
    int bx = blockIdx.x * 32;   // k block
    int by = blockIdx.y * 32;   // n block
    int tx = threadIdx.x & 31, ty = threadIdx.x >> 5;  // ty 0..7
#pragma unroll
    for (int j = 0; j < 4; ++j)
        t[ty + j * 8][tx] = W[(size_t)(bx + ty + j * 8) * 640 + by + tx];
    __syncthreads();
#pragma unroll
    for (int j = 0; j < 4; ++j)
        Wt[(size_t)(by + ty + j * 8) * 640 + bx + tx] = (f16)t[tx][ty + j * 8];
}

// ---------------- f16 MFMA GEMM: C[M,640] = A[M,640] @ Bt^T (f16 out) -------
// A [M][640] f16 row-major; Bt [640][640] f16 with Bt[n][k] = B[k][n]
// 256 threads = 4 waves (2x2), tile 128x64, 16x16x32 MFMA, f16 C
__global__ __launch_bounds__(256) void k_gemm16(const f16* __restrict__ A,
                                                const f16* __restrict__ Bt,
                                                f16* __restrict__ C, int M)
{
    __shared__ f16 As[128][40];   // rows padded 32->40 f16 (80B): 2-way alias only
    __shared__ f16 Bs[64][40];
    int tid = threadIdx.x;
    int row0 = blockIdx.x * 128;
    int col0 = blockIdx.y * 64;
    int w = tid >> 6, l = tid & 63;
    int wr = (w >> 1) * 64;       // wave row offset (0/64)
    int wc = (w & 1) * 32;        // wave col offset (0/32)
    int lrow = l & 15;
    int lk = (l >> 4) * 8;
    int srow = tid >> 2;          // 0..63
    int sseg = (tid & 3) * 8;     // 0,8,16,24

    f32x4 acc[4][2];
#pragma unroll
    for (int m = 0; m < 4; ++m)
#pragma unroll
        for (int n = 0; n < 2; ++n)
            acc[m][n] = (f32x4){0.f, 0.f, 0.f, 0.f};

    for (int k0 = 0; k0 < FF; k0 += 32) {
        f16x8 a0 = {}, a1 = {};
        int r0 = row0 + srow, r1 = row0 + srow + 64;
        if (r0 < M) a0 = *(const f16x8*)&A[(size_t)r0 * FF + k0 + sseg];
        if (r1 < M) a1 = *(const f16x8*)&A[(size_t)r1 * FF + k0 + sseg];
        f16x8 b0 = *(const f16x8*)&Bt[(size_t)(col0 + srow) * FF + k0 + sseg];
        __syncthreads();
        *(f16x8*)&As[srow][sseg]      = a0;
        *(f16x8*)&As[srow + 64][sseg] = a1;
        *(f16x8*)&Bs[srow][sseg]      = b0;
        __syncthreads();
        f16x8 af[4], bf[2];
#pragma unroll
        for (int m = 0; m < 4; ++m)
            af[m] = *(const f16x8*)&As[wr + m * 16 + lrow][lk];
#pragma unroll
        for (int n = 0; n < 2; ++n)
            bf[n] = *(const f16x8*)&Bs[wc + n * 16 + lrow][lk];
#pragma unroll
        for (int m = 0; m < 4; ++m)
#pragma unroll
            for (int n = 0; n < 2; ++n)
                acc[m][n] = __builtin_amdgcn_mfma_f32_16x16x32_f16(af[m], bf[n], acc[m][n], 0, 0, 0);
    }
    int orow = (l >> 4) * 4;
#pragma unroll
    for (int m = 0; m < 4; ++m) {
#pragma unroll
        for (int r = 0; r < 4; ++r) {
            int rr = row0 + wr + m * 16 + orow + r;
            if (rr < M) {
#pragma unroll
                for (int n = 0; n < 2; ++n)
                    C[(size_t)rr * FF + col0 + wc + n * 16 + lrow] = (f16)acc[m][n][r];
            }
        }
    }
}

// ---------------- GCN aggregate: hout[d] = relu(Anorm @ h + b)  (f16 in/out)
__global__ void k_agg(const f16* __restrict__ hsrc, const int* __restrict__ rowptr,
                      const int* __restrict__ colsrc, const float* __restrict__ enorm,
                      const float* __restrict__ dis, const float* __restrict__ bias,
                      f16* __restrict__ hout)
{
    int d = blockIdx.x;
    int f = threadIdx.x;            // 640 threads
    float selfw = dis[d] * dis[d];
    float v = selfw * (float)hsrc[(size_t)d * FF + f];
    int beg = rowptr[d], end = rowptr[d + 1];
    for (int idx = beg; idx < end; ++idx) {
        int s = colsrc[idx];
        float w = enorm[idx];
        v += w * (float)hsrc[(size_t)s * FF + f];
    }
    v += bias[f];
    v = fmaxf(v, 0.f);
    hout[(size_t)d * FF + f] = (f16)v;
}

// ---------------- GReTo mix: acc folded in ----------------------------------
// out[n,d,t] = relu( sum_c (p0*h1+p1*h2+p2*h3)[n,c,t]*gW[c][d]
//                  + sum_c hneg[n,c,t]*gW[64+c][d] + gb[d] )
__global__ void k_greto(const f16* __restrict__ h1, const f16* __restrict__ h2,
                        const f16* __restrict__ h3, const f16* __restrict__ hneg,
                        const float* __restrict__ psi,
                        const float* __restrict__ gW, const float* __restrict__ gb,
                        float* __restrict__ out)
{
    __shared__ float sa[FF], sn[FF];
    int n = blockIdx.x;
    float p0 = psi[n * 3 + 0], p1 = psi[n * 3 + 1], p2 = psi[n * 3 + 2];
    for (int i = threadIdx.x; i < FF; i += 640) {
        size_t o = (size_t)n * FF + i;
        sa[i] = p0 * (float)h1[o] + p1 * (float)h2[o] + p2 * (float)h3[o];
        sn[i] = (float)hneg[o];
    }
    __syncthreads();
    int t = threadIdx.x >> 6;
    int d = threadIdx.x & 63;
    float v = gb[d];
    for (int c = 0; c < HCH; ++c) {
        v += sa[c * TSP + t] * gW[c * HCH + d];
        v += sn[c * TSP + t] * gW[(HCH + c) * HCH + d];
    }
    out[(size_t)n * FF + d * TSP + t] = fmaxf(v, 0.f);
}

// ---------------- TCN2 ------------------------------------------------------
__global__ __launch_bounds__(256) void k_tcn2(const float* __restrict__ g,
                       const float* __restrict__ wt,
                       const float* __restrict__ b1, const float* __restrict__ b2,
                       float* __restrict__ out)
{
    __shared__ float xs[4][HCH * 12];
    const float* wA = wt + 24576;
    const float* wB = wt + 36864;
    int node0 = blockIdx.x * 4;
    for (int i = threadIdx.x; i < 4 * HCH * TSP; i += 256) {
        int nn = i / (HCH * TSP), off = i % (HCH * TSP);
        int h = off / TSP, t = off % TSP;
        int gg = node0 + nn;
        xs[nn][h * 12 + t] = (gg < NN) ? g[(size_t)gg * FF + off] : 0.f;
    }
    __syncthreads();
    int ln = threadIdx.x >> 6, c = threadIdx.x & 63;
    int node = node0 + ln;
    if (node >= NN) return;
    float s1[TOUT], s2[TOUT];
    float bb1 = b1[c], bb2 = b2[c];
#pragma unroll
    for (int t = 0; t < TOUT; ++t) { s1[t] = bb1; s2[t] = bb2; }
    for (int h = 0; h < HCH; ++h) {
        int wi = h * 64 + c;
        float a0 = wA[wi], a1 = wA[4096 + wi], a2 = wA[8192 + wi];
        float g0 = wB[wi], g1 = wB[4096 + wi], g2 = wB[8192 + wi];
        const float* xr = &xs[ln][h * 12];
        float4 q0 = *(const float4*)&xr[0];
        float4 q1 = *(const float4*)&xr[4];
        float4 q2 = *(const float4*)&xr[8];
        float v[12] = {q0.x,q0.y,q0.z,q0.w, q1.x,q1.y,q1.z,q1.w,
                       q2.x,q2.y,q2.z,q2.w};
#pragma unroll
        for (int t = 0; t < TOUT; ++t) {
            s1[t] += a0 * v[t] + a1 * v[t + 1] + a2 * v[t + 2];
            s2[t] += g0 * v[t] + g1 * v[t + 1] + g2 * v[t + 2];
        }
    }
#pragma unroll
    for (int t = 0; t < TOUT; ++t) {
        float e = __expf(2.f * s1[t]);
        float th = 1.f - 2.f / (e + 1.f);
        float sg = 1.f / (1.f + __expf(-s2[t]));
        out[(size_t)node * (CCH * TOUT) + c * TOUT + t] = th * sg;
    }
}

extern "C" void kernel_launch(void* const* d_in, const int* in_sizes, int n_in,
                              void* d_out, int out_size, void* d_ws, size_t ws_size,
                              hipStream_t stream)
{
    const float* x     = (const float*)d_in[0];
    const int*   ei    = (const int*)  d_in[1];
    const float* ea    = (const float*)d_in[2];
    const float* ndt   = (const float*)d_in[3];
    const float* tc1w1 = (const float*)d_in[4];
    const float* tc1b1 = (const float*)d_in[5];
    const float* tc1w2 = (const float*)d_in[6];
    const float* tc1b2 = (const float*)d_in[7];
    const float* Wpos  = (const float*)d_in[8];
    const float* bpos  = (const float*)d_in[9];
    const float* Wneg  = (const float*)d_in[10];
    const float* bneg  = (const float*)d_in[11];
    const float* greW  = (const float*)d_in[12];
    const float* greb  = (const float*)d_in[13];
    const float* psiW1 = (const float*)d_in[14];
    const float* psib1 = (const float*)d_in[15];
    const float* psiW2 = (const float*)d_in[16];
    const float* psib2 = (const float*)d_in[17];
    const float* tc2w1 = (const float*)d_in[18];
    const float* tc2b1 = (const float*)d_in[19];
    const float* tc2w2 = (const float*)d_in[20];
    const float* tc2b2 = (const float*)d_in[21];
    float* out = (float*)d_out;

    char* p = (char*)d_ws;
    f16*   out0h = (f16*)p;   p += (size_t)NN * FF * 2;
    f16*   h1    = (f16*)p;   p += (size_t)NN * FF * 2;
    f16*   h2    = (f16*)p;   p += (size_t)NN * FF * 2;
    f16*   h3    = (f16*)p;   p += (size_t)NN * FF * 2;
    f16*   hneg  = (f16*)p;   p += (size_t)NN * FF * 2;
    f16*   Cb16  = (f16*)p;   p += (size_t)NN * FF * 2;
    float* Cbuf  = (float*)p; p += (size_t)NN * FF * 4;
    f16*   Wtp   = (f16*)p;   p += (size_t)FF * FF * 2;
    f16*   Wtn   = (f16*)p;   p += (size_t)FF * FF * 2;
    float* psib  = (float*)p; p += (size_t)NN * 3 * 4;
    float* degp  = (float*)p; p += (size_t)NN * 4;
    float* degn  = (float*)p; p += (size_t)NN * 4;
    float* disp  = (float*)p; p += (size_t)NN * 4;
    float* disn  = (float*)p; p += (size_t)NN * 4;
    float* normp = (float*)p; p += (size_t)NE * 4;
    float* normn = (float*)p; p += (size_t)NE * 4;
    int* cnt     = (int*)p;   p += (size_t)NN * 4;
    int* rowptr  = (int*)p;   p += (size_t)(NN + 1) * 4;
    int* cursor  = (int*)p;   p += (size_t)NN * 4;
    int* colsrc  = (int*)p;   p += (size_t)NE * 4;
    float* wt    = (float*)p; p += (size_t)4 * 12288 * 4;

    (void)hipMemsetAsync(cnt, 0, NN * 4, stream);
    (void)hipMemsetAsync(cursor, 0, NN * 4, stream);
    (void)hipMemsetAsync(degp, 0, NN * 4, stream);
    (void)hipMemsetAsync(degn, 0, NN * 4, stream);

    k_wt<<<(4 * 12288 + 255) / 256, 256, 0, stream>>>(tc1w1, tc1w2, tc2w1, tc2w2, wt);
    k_tcn1<<<2500, 256, 0, stream>>>(x, wt, tc1b1, tc1b2, out0h);
    k_psi<<<(NN + 255) / 256, 256, 0, stream>>>(ndt, psiW1, psib1, psiW2, psib2, psib);
    k_deg<<<(NE + 255) / 256, 256, 0, stream>>>(ei, ea, cnt, degp, degn);
    k_dis<<<(NN + 255) / 256, 256, 0, stream>>>(degp, degn, disp, disn);
    k_scan<<<1, 1024, 0, stream>>>(cnt, rowptr);
    k_fill<<<(NE + 255) / 256, 256, 0, stream>>>(ei, ea, rowptr, cursor, disp, disn,
                                                 colsrc, normp, normn);
    dim3 wgrid(20, 20);
    k_wsplit<<<wgrid, 256, 0, stream>>>(Wpos, Wtp);
    k_wsplit<<<wgrid, 256, 0, stream>>>(Wneg, Wtn);

    dim3 ggrid((NN + 127) / 128, FF / 64);
    // positive hops
    k_gemm16<<<ggrid, 256, 0, stream>>>(out0h, Wtp, Cb16, NN);
    k_agg<<<NN, 640, 0, stream>>>(Cb16, rowptr, colsrc, normp, disp, bpos, h1);
    k_gemm16<<<ggrid, 256, 0, stream>>>(h1, Wtp, Cb16, NN);
    k_agg<<<NN, 640, 0, stream>>>(Cb16, rowptr, colsrc, normp, disp, bpos, h2);
    k_gemm16<<<ggrid, 256, 0, stream>>>(h2, Wtp, Cb16, NN);
    k_agg<<<NN, 640, 0, stream>>>(Cb16, rowptr, colsrc, normp, disp, bpos, h3);
    // negative branch
    k_gemm16<<<ggrid, 256, 0, stream>>>(out0h, Wtn, Cb16, NN);
    k_agg<<<NN, 640, 0, stream>>>(Cb16, rowptr, colsrc, normn, disn, bneg, hneg);
    // channel mix + psi accumulation + relu
    k_greto<<<NN, 640, 0, stream>>>(h1, h2, h3, hneg, psib, greW, greb, Cbuf);
    // final gated TCN
    k_tcn2<<<2500, 256, 0, stream>>>(Cbuf, wt, tc2b1, tc2b2, out);
}

// Round 10
// 825.479 us; speedup vs baseline: 1.8344x; 1.0839x over previous
//
#include <hip/hip_runtime.h>
#include <math.h>

#define NN   10000   // nodes
#define NE   160000  // edges
#define CCH  64      // in/out channels
#define TIN  12      // input time steps
#define HCH  64      // hidden channels
#define TSP  10      // T - 2
#define FF   640     // H * TSP
#define TOUT 8       // TSP - 2
#define NR   (NN * TSP)   // 100000 node-time rows

// Feature ordering in the GCN pipeline: f' = t*64 + h  (channel-contiguous rows)

typedef _Float16 f16;
typedef _Float16 f16x8 __attribute__((ext_vector_type(8)));
typedef float f32x4 __attribute__((ext_vector_type(4)));

// ---------------- weight transpose: wt[k][cin][cout] = w[cout][cin][k] ------
__global__ void k_wt(const float* __restrict__ s0, const float* __restrict__ s1,
                     const float* __restrict__ s2, const float* __restrict__ s3,
                     float* __restrict__ dst)
{
    int e = blockIdx.x * 256 + threadIdx.x;
    if (e >= 4 * 12288) return;
    int s = e / 12288, r = e % 12288;
    const float* src = (s == 0) ? s0 : (s == 1) ? s1 : (s == 2) ? s2 : s3;
    int o = r & 63;
    int i = (r >> 6) & 63;
    int k = r >> 12;
    dst[e] = src[(o * 64 + i) * 3 + k];
}

// ---------------- TCN1: x[N,64,12] -> out f16 [N][t*64+h] -------------------
__global__ __launch_bounds__(256) void k_tcn1(const float* __restrict__ x,
                       const float* __restrict__ wt,
                       const float* __restrict__ b1, const float* __restrict__ b2,
                       f16* __restrict__ out)
{
    __shared__ float xs[4][CCH * TIN];
    const float* wA = wt;
    const float* wB = wt + 12288;
    int node0 = blockIdx.x * 4;
    for (int i = threadIdx.x; i < 4 * CCH * TIN; i += 256) {
        int nn = i / (CCH * TIN), off = i % (CCH * TIN);
        int g = node0 + nn;
        xs[nn][off] = (g < NN) ? x[(size_t)g * CCH * TIN + off] : 0.f;
    }
    __syncthreads();
    int ln = threadIdx.x >> 6, h = threadIdx.x & 63;
    int node = node0 + ln;
    if (node >= NN) return;
    float s1[TSP], s2[TSP];
    float bb1 = b1[h], bb2 = b2[h];
#pragma unroll
    for (int t = 0; t < TSP; ++t) { s1[t] = bb1; s2[t] = bb2; }
    for (int c = 0; c < CCH; ++c) {
        int wi = c * 64 + h;
        float a0 = wA[wi], a1 = wA[4096 + wi], a2 = wA[8192 + wi];
        float g0 = wB[wi], g1 = wB[4096 + wi], g2 = wB[8192 + wi];
        const float* xr = &xs[ln][c * TIN];
        float4 q0 = *(const float4*)&xr[0];
        float4 q1 = *(const float4*)&xr[4];
        float4 q2 = *(const float4*)&xr[8];
        float v[TIN] = {q0.x,q0.y,q0.z,q0.w, q1.x,q1.y,q1.z,q1.w,
                        q2.x,q2.y,q2.z,q2.w};
#pragma unroll
        for (int t = 0; t < TSP; ++t) {
            s1[t] += a0 * v[t] + a1 * v[t + 1] + a2 * v[t + 2];
            s2[t] += g0 * v[t] + g1 * v[t + 1] + g2 * v[t + 2];
        }
    }
#pragma unroll
    for (int t = 0; t < TSP; ++t) {
        float e = __expf(2.f * s1[t]);
        float th = 1.f - 2.f / (e + 1.f);
        float sg = 1.f / (1.f + __expf(-s2[t]));
        out[(size_t)node * FF + t * 64 + h] = (f16)(th * sg);   // coalesced per wave
    }
}

// ---------------- psi MLP ---------------------------------------------------
__global__ void k_psi(const float* __restrict__ ND, const float* __restrict__ W1,
                      const float* __restrict__ b1, const float* __restrict__ W2,
                      const float* __restrict__ b2, float* __restrict__ psi)
{
    int n = blockIdx.x * blockDim.x + threadIdx.x;
    if (n >= NN) return;
    float d0 = ND[n * 3], d1 = ND[n * 3 + 1], d2 = ND[n * 3 + 2];
    float o0 = b2[0], o1 = b2[1], o2 = b2[2];
    for (int j = 0; j < 64; ++j) {
        float hv = d0 * W1[j] + d1 * W1[64 + j] + d2 * W1[128 + j] + b1[j];
        hv = fmaxf(hv, 0.f);
        o0 += hv * W2[j * 3 + 0];
        o1 += hv * W2[j * 3 + 1];
        o2 += hv * W2[j * 3 + 2];
    }
    psi[n * 3 + 0] = o0; psi[n * 3 + 1] = o1; psi[n * 3 + 2] = o2;
}

// ---------------- degree / counts -------------------------------------------
__global__ void k_deg(const int* __restrict__ ei, const float* __restrict__ ea,
                      int* __restrict__ cnt, float* __restrict__ degp, float* __restrict__ degn)
{
    int e = blockIdx.x * blockDim.x + threadIdx.x;
    if (e >= NE) return;
    int d = ei[NE + e];
    atomicAdd(&cnt[d], 1);
    atomicAdd(&degp[d], ea[e * 2 + 0] + 1.f);
    atomicAdd(&degn[d], ea[e * 2 + 1] + 1.f);
}

__global__ void k_dis(const float* __restrict__ degp, const float* __restrict__ degn,
                      float* __restrict__ disp, float* __restrict__ disn)
{
    int n = blockIdx.x * blockDim.x + threadIdx.x;
    if (n >= NN) return;
    disp[n] = 1.f / sqrtf(degp[n] + 1.f);
    disn[n] = 1.f / sqrtf(degn[n] + 1.f);
}

// ---------------- exclusive scan --------------------------------------------
__global__ __launch_bounds__(1024) void k_scan(const int* __restrict__ cnt, int* __restrict__ rowptr)
{
    __shared__ int buf[1024];
    __shared__ int carry;
    if (threadIdx.x == 0) carry = 0;
    __syncthreads();
    for (int base = 0; base < NN; base += 1024) {
        int i = base + threadIdx.x;
        int v = (i < NN) ? cnt[i] : 0;
        buf[threadIdx.x] = v;
        __syncthreads();
        for (int off = 1; off < 1024; off <<= 1) {
            int t = (threadIdx.x >= (unsigned)off) ? buf[threadIdx.x - off] : 0;
            __syncthreads();
            buf[threadIdx.x] += t;
            __syncthreads();
        }
        if (i < NN) rowptr[i] = carry + buf[threadIdx.x] - v;
        __syncthreads();
        if (threadIdx.x == 0) carry += buf[1023];
        __syncthreads();
    }
    if (threadIdx.x == 0) rowptr[NN] = carry;
}

// ---------------- CSR fill ---------------------------------------------------
__global__ void k_fill(const int* __restrict__ ei, const float* __restrict__ ea,
                       const int* __restrict__ rowptr, int* __restrict__ cursor,
                       const float* __restrict__ disp, const float* __restrict__ disn,
                       int* __restrict__ colsrc, float* __restrict__ normp, float* __restrict__ normn)
{
    int e = blockIdx.x * blockDim.x + threadIdx.x;
    if (e >= NE) return;
    int s = ei[e], d = ei[NE + e];
    int slot = atomicAdd(&cursor[d], 1);
    int idx = rowptr[d] + slot;
    colsrc[idx] = s;
    normp[idx] = disp[s] * (ea[e * 2 + 0] + 1.f) * disp[d];
    normn[idx] = disn[s] * (ea[e * 2 + 1] + 1.f) * disn[d];
}

// ---------------- W transpose+cast: Wt0[n][k] = (f16)W[k][n] (orig order) ---
__global__ __launch_bounds__(256) void k_wsplit(const float* __restrict__ W, f16* __restrict__ Wt)
{
    __shared__ float t[32][33];
    int bx = blockIdx.x * 32;   // k block
    int by = blockIdx.y * 32;   // n block
    int tx = threadIdx.x & 31, ty = threadIdx.x >> 5;  // ty 0..7
#pragma unroll
    for (int j = 0; j < 4; ++j)
        t[ty + j * 8][tx] = W[(size_t)(bx + ty + j * 8) * 640 + by + tx];
    __syncthreads();
#pragma unroll
    for (int j = 0; j < 4; ++j)
        Wt[(size_t)(by + ty + j * 8) * 640 + bx + tx] = (f16)t[tx][ty + j * 8];
}

// ---------------- permute rows+cols to f' order -----------------------------
// Wt'[n'][k'] = Wt0[perm(n')][perm(k')], perm(i) = (i&63)*10 + (i>>6)
__global__ __launch_bounds__(640) void k_perm(const f16* __restrict__ Wt0, f16* __restrict__ Wt)
{
    __shared__ f16 row[FF];
    int np = blockIdx.x;                       // n' (output row)
    int n = (np & 63) * 10 + (np >> 6);        // source row
    int tid = threadIdx.x;
    row[tid] = Wt0[(size_t)n * FF + tid];
    __syncthreads();
    int k = (tid & 63) * 10 + (tid >> 6);      // source col for k'=tid
    Wt[(size_t)np * FF + tid] = row[k];
}

// ---------------- gW transpose: gWt[d][c] = (f16)gW[c][d], c in [0,128) -----
__global__ void k_gwt(const float* __restrict__ gW, f16* __restrict__ gWt)
{
    int tid = blockIdx.x * 256 + threadIdx.x;
    if (tid >= 128 * 64) return;
    int c = tid >> 6, d = tid & 63;
    gWt[d * 128 + c] = (f16)gW[tid];
}

// ---------------- f16 MFMA GEMM: C[M,640] = A[M,640] @ Bt^T (f16 out) -------
// 256 threads = 4 waves (2x2), tile 128x64, 16x16x32 MFMA, f16 C
__global__ __launch_bounds__(256) void k_gemm16(const f16* __restrict__ A,
                                                const f16* __restrict__ Bt,
                                                f16* __restrict__ C, int M)
{
    __shared__ f16 As[128][40];   // rows padded 32->40 f16: benign 2-way alias
    __shared__ f16 Bs[64][40];
    int tid = threadIdx.x;
    int row0 = blockIdx.x * 128;
    int col0 = blockIdx.y * 64;
    int w = tid >> 6, l = tid & 63;
    int wr = (w >> 1) * 64;
    int wc = (w & 1) * 32;
    int lrow = l & 15;
    int lk = (l >> 4) * 8;
    int srow = tid >> 2;
    int sseg = (tid & 3) * 8;

    f32x4 acc[4][2];
#pragma unroll
    for (int m = 0; m < 4; ++m)
#pragma unroll
        for (int n = 0; n < 2; ++n)
            acc[m][n] = (f32x4){0.f, 0.f, 0.f, 0.f};

    for (int k0 = 0; k0 < FF; k0 += 32) {
        f16x8 a0 = {}, a1 = {};
        int r0 = row0 + srow, r1 = row0 + srow + 64;
        if (r0 < M) a0 = *(const f16x8*)&A[(size_t)r0 * FF + k0 + sseg];
        if (r1 < M) a1 = *(const f16x8*)&A[(size_t)r1 * FF + k0 + sseg];
        f16x8 b0 = *(const f16x8*)&Bt[(size_t)(col0 + srow) * FF + k0 + sseg];
        __syncthreads();
        *(f16x8*)&As[srow][sseg]      = a0;
        *(f16x8*)&As[srow + 64][sseg] = a1;
        *(f16x8*)&Bs[srow][sseg]      = b0;
        __syncthreads();
        f16x8 af[4], bf[2];
#pragma unroll
        for (int m = 0; m < 4; ++m)
            af[m] = *(const f16x8*)&As[wr + m * 16 + lrow][lk];
#pragma unroll
        for (int n = 0; n < 2; ++n)
            bf[n] = *(const f16x8*)&Bs[wc + n * 16 + lrow][lk];
#pragma unroll
        for (int m = 0; m < 4; ++m)
#pragma unroll
            for (int n = 0; n < 2; ++n)
                acc[m][n] = __builtin_amdgcn_mfma_f32_16x16x32_f16(af[m], bf[n], acc[m][n], 0, 0, 0);
    }
    int orow = (l >> 4) * 4;
#pragma unroll
    for (int m = 0; m < 4; ++m) {
#pragma unroll
        for (int r = 0; r < 4; ++r) {
            int rr = row0 + wr + m * 16 + orow + r;
            if (rr < M) {
#pragma unroll
                for (int n = 0; n < 2; ++n)
                    C[(size_t)rr * FF + col0 + wc + n * 16 + lrow] = (f16)acc[m][n][r];
            }
        }
    }
}

// ---------------- GCN aggregate (f' order; bias permuted inline) ------------
__global__ void k_agg(const f16* __restrict__ hsrc, const int* __restrict__ rowptr,
                      const int* __restrict__ colsrc, const float* __restrict__ enorm,
                      const float* __restrict__ dis, const float* __restrict__ bias,
                      f16* __restrict__ hout)
{
    int d = blockIdx.x;
    int f = threadIdx.x;            // f' = t*64 + h
    float selfw = dis[d] * dis[d];
    float v = selfw * (float)hsrc[(size_t)d * FF + f];
    int beg = rowptr[d], end = rowptr[d + 1];
    for (int idx = beg; idx < end; ++idx) {
        int s = colsrc[idx];
        float w = enorm[idx];
        v += w * (float)hsrc[(size_t)s * FF + f];
    }
    v += bias[(f & 63) * 10 + (f >> 6)];   // bias is in original h*10+t order
    v = fmaxf(v, 0.f);
    hout[(size_t)d * FF + f] = (f16)v;
}

// ---------------- GReTo mix as MFMA GEMM ------------------------------------
// rows r = n*10+t (100K); A[r][c] = psi-combined pos (c<64) | hneg (c>=64)
// out[r*64+d] = relu(sum_c A[r][c]*gWt[d][c] + gb[d]);  out == [n][t*64+d] f32
__global__ __launch_bounds__(256) void k_greto2(const f16* __restrict__ h1,
                        const f16* __restrict__ h2, const f16* __restrict__ h3,
                        const f16* __restrict__ hneg, const float* __restrict__ psi,
                        const f16* __restrict__ gWt, const float* __restrict__ gb,
                        float* __restrict__ out)
{
    __shared__ f16 As[128][132];   // K=128 padded to 132 (66 dwords, gcd 2 -> no conflict)
    __shared__ f16 Bs[64][132];
    int tid = threadIdx.x;
    int row0 = blockIdx.x * 128;

    // stage B (gWt [64][128])
    for (int cb = tid; cb < 1024; cb += 256) {
        int d = cb >> 4, seg = (cb & 15) * 8;
        *(f16x8*)&Bs[d][seg] = *(const f16x8*)&gWt[d * 128 + seg];
    }
    // stage A: 2 threads per row
    int lr = tid >> 1, side = tid & 1;
    int r = row0 + lr;
    if (r < NR) {
        int n = r / 10, t = r - (r / 10) * 10;
        size_t base = (size_t)n * FF + t * 64;
        if (side == 0) {
            float p0 = psi[n * 3], p1 = psi[n * 3 + 1], p2 = psi[n * 3 + 2];
#pragma unroll
            for (int i = 0; i < 8; ++i) {
                f16x8 a = *(const f16x8*)&h1[base + i * 8];
                f16x8 b = *(const f16x8*)&h2[base + i * 8];
                f16x8 c = *(const f16x8*)&h3[base + i * 8];
                f16x8 o;
#pragma unroll
                for (int j = 0; j < 8; ++j)
                    o[j] = (f16)(p0 * (float)a[j] + p1 * (float)b[j] + p2 * (float)c[j]);
                *(f16x8*)&As[lr][i * 8] = o;
            }
        } else {
#pragma unroll
            for (int i = 0; i < 8; ++i)
                *(f16x8*)&As[lr][64 + i * 8] = *(const f16x8*)&hneg[base + i * 8];
        }
    } else {
        f16x8 z = {};
#pragma unroll
        for (int i = 0; i < 8; ++i)
            *(f16x8*)&As[lr][side * 64 + i * 8] = z;
    }
    __syncthreads();

    int w = tid >> 6, l = tid & 63;
    int wr = w * 32;
    int lrow = l & 15;
    int lk = (l >> 4) * 8;
    f32x4 acc[2][4];
#pragma unroll
    for (int m = 0; m < 2; ++m)
#pragma unroll
        for (int n = 0; n < 4; ++n)
            acc[m][n] = (f32x4){0.f, 0.f, 0.f, 0.f};
#pragma unroll
    for (int ks = 0; ks < 4; ++ks) {
        f16x8 af[2], bf[4];
#pragma unroll
        for (int m = 0; m < 2; ++m)
            af[m] = *(const f16x8*)&As[wr + m * 16 + lrow][ks * 32 + lk];
#pragma unroll
        for (int n = 0; n < 4; ++n)
            bf[n] = *(const f16x8*)&Bs[n * 16 + lrow][ks * 32 + lk];
#pragma unroll
        for (int m = 0; m < 2; ++m)
#pragma unroll
            for (int n = 0; n < 4; ++n)
                acc[m][n] = __builtin_amdgcn_mfma_f32_16x16x32_f16(af[m], bf[n], acc[m][n], 0, 0, 0);
    }
    int orow = (l >> 4) * 4;
#pragma unroll
    for (int m = 0; m < 2; ++m) {
#pragma unroll
        for (int rr = 0; rr < 4; ++rr) {
            int ro = row0 + wr + m * 16 + orow + rr;
            if (ro < NR) {
#pragma unroll
                for (int n = 0; n < 4; ++n) {
                    int col = n * 16 + lrow;
                    out[(size_t)ro * 64 + col] = fmaxf(acc[m][n][rr] + gb[col], 0.f);
                }
            }
        }
    }
}

// ---------------- TCN2 (input g in f' = t*64+h order) -----------------------
__global__ __launch_bounds__(256) void k_tcn2(const float* __restrict__ g,
                       const float* __restrict__ wt,
                       const float* __restrict__ b1, const float* __restrict__ b2,
                       float* __restrict__ out)
{
    __shared__ float xs[4][HCH * 12];
    const float* wA = wt + 24576;
    const float* wB = wt + 36864;
    int node0 = blockIdx.x * 4;
    for (int i = threadIdx.x; i < 4 * HCH * TSP; i += 256) {
        int nn = i / (HCH * TSP), off = i % (HCH * TSP);
        int h = off & 63, t = off >> 6;        // f' decode
        int gg = node0 + nn;
        xs[nn][h * 12 + t] = (gg < NN) ? g[(size_t)gg * FF + off] : 0.f;
    }
    __syncthreads();
    int ln = threadIdx.x >> 6, c = threadIdx.x & 63;
    int node = node0 + ln;
    if (node >= NN) return;
    float s1[TOUT], s2[TOUT];
    float bb1 = b1[c], bb2 = b2[c];
#pragma unroll
    for (int t = 0; t < TOUT; ++t) { s1[t] = bb1; s2[t] = bb2; }
    for (int h = 0; h < HCH; ++h) {
        int wi = h * 64 + c;
        float a0 = wA[wi], a1 = wA[4096 + wi], a2 = wA[8192 + wi];
        float g0 = wB[wi], g1 = wB[4096 + wi], g2 = wB[8192 + wi];
        const float* xr = &xs[ln][h * 12];
        float4 q0 = *(const float4*)&xr[0];
        float4 q1 = *(const float4*)&xr[4];
        float4 q2 = *(const float4*)&xr[8];
        float v[12] = {q0.x,q0.y,q0.z,q0.w, q1.x,q1.y,q1.z,q1.w,
                       q2.x,q2.y,q2.z,q2.w};
#pragma unroll
        for (int t = 0; t < TOUT; ++t) {
            s1[t] += a0 * v[t] + a1 * v[t + 1] + a2 * v[t + 2];
            s2[t] += g0 * v[t] + g1 * v[t + 1] + g2 * v[t + 2];
        }
    }
#pragma unroll
    for (int t = 0; t < TOUT; ++t) {
        float e = __expf(2.f * s1[t]);
        float th = 1.f - 2.f / (e + 1.f);
        float sg = 1.f / (1.f + __expf(-s2[t]));
        out[(size_t)node * (CCH * TOUT) + c * TOUT + t] = th * sg;
    }
}

extern "C" void kernel_launch(void* const* d_in, const int* in_sizes, int n_in,
                              void* d_out, int out_size, void* d_ws, size_t ws_size,
                              hipStream_t stream)
{
    const float* x     = (const float*)d_in[0];
    const int*   ei    = (const int*)  d_in[1];
    const float* ea    = (const float*)d_in[2];
    const float* ndt   = (const float*)d_in[3];
    const float* tc1w1 = (const float*)d_in[4];
    const float* tc1b1 = (const float*)d_in[5];
    const float* tc1w2 = (const float*)d_in[6];
    const float* tc1b2 = (const float*)d_in[7];
    const float* Wpos  = (const float*)d_in[8];
    const float* bpos  = (const float*)d_in[9];
    const float* Wneg  = (const float*)d_in[10];
    const float* bneg  = (const float*)d_in[11];
    const float* greW  = (const float*)d_in[12];
    const float* greb  = (const float*)d_in[13];
    const float* psiW1 = (const float*)d_in[14];
    const float* psib1 = (const float*)d_in[15];
    const float* psiW2 = (const float*)d_in[16];
    const float* psib2 = (const float*)d_in[17];
    const float* tc2w1 = (const float*)d_in[18];
    const float* tc2b1 = (const float*)d_in[19];
    const float* tc2w2 = (const float*)d_in[20];
    const float* tc2b2 = (const float*)d_in[21];
    float* out = (float*)d_out;

    char* p = (char*)d_ws;
    f16*   out0h = (f16*)p;   p += (size_t)NN * FF * 2;
    f16*   h1    = (f16*)p;   p += (size_t)NN * FF * 2;
    f16*   h2    = (f16*)p;   p += (size_t)NN * FF * 2;
    f16*   h3    = (f16*)p;   p += (size_t)NN * FF * 2;
    f16*   hneg  = (f16*)p;   p += (size_t)NN * FF * 2;
    f16*   Cb16  = (f16*)p;   p += (size_t)NN * FF * 2;
    float* Cbuf  = (float*)p; p += (size_t)NN * FF * 4;
    f16*   Wtp   = (f16*)p;   p += (size_t)FF * FF * 2;
    f16*   Wtn   = (f16*)p;   p += (size_t)FF * FF * 2;
    f16*   Wtmp  = (f16*)p;   p += (size_t)FF * FF * 2;
    f16*   gWt   = (f16*)p;   p += (size_t)128 * 64 * 2;
    float* psib  = (float*)p; p += (size_t)NN * 3 * 4;
    float* degp  = (float*)p; p += (size_t)NN * 4;
    float* degn  = (float*)p; p += (size_t)NN * 4;
    float* disp  = (float*)p; p += (size_t)NN * 4;
    float* disn  = (float*)p; p += (size_t)NN * 4;
    float* normp = (float*)p; p += (size_t)NE * 4;
    float* normn = (float*)p; p += (size_t)NE * 4;
    int* cnt     = (int*)p;   p += (size_t)NN * 4;
    int* rowptr  = (int*)p;   p += (size_t)(NN + 1) * 4;
    int* cursor  = (int*)p;   p += (size_t)NN * 4;
    int* colsrc  = (int*)p;   p += (size_t)NE * 4;
    float* wt    = (float*)p; p += (size_t)4 * 12288 * 4;

    (void)hipMemsetAsync(cnt, 0, NN * 4, stream);
    (void)hipMemsetAsync(cursor, 0, NN * 4, stream);
    (void)hipMemsetAsync(degp, 0, NN * 4, stream);
    (void)hipMemsetAsync(degn, 0, NN * 4, stream);

    k_wt<<<(4 * 12288 + 255) / 256, 256, 0, stream>>>(tc1w1, tc1w2, tc2w1, tc2w2, wt);
    k_tcn1<<<2500, 256, 0, stream>>>(x, wt, tc1b1, tc1b2, out0h);
    k_psi<<<(NN + 255) / 256, 256, 0, stream>>>(ndt, psiW1, psib1, psiW2, psib2, psib);
    k_deg<<<(NE + 255) / 256, 256, 0, stream>>>(ei, ea, cnt, degp, degn);
    k_dis<<<(NN + 255) / 256, 256, 0, stream>>>(degp, degn, disp, disn);
    k_scan<<<1, 1024, 0, stream>>>(cnt, rowptr);
    k_fill<<<(NE + 255) / 256, 256, 0, stream>>>(ei, ea, rowptr, cursor, disp, disn,
                                                 colsrc, normp, normn);
    dim3 wgrid(20, 20);
    k_wsplit<<<wgrid, 256, 0, stream>>>(Wpos, Wtmp);
    k_perm<<<FF, 640, 0, stream>>>(Wtmp, Wtp);
    k_wsplit<<<wgrid, 256, 0, stream>>>(Wneg, Wtmp);
    k_perm<<<FF, 640, 0, stream>>>(Wtmp, Wtn);
    k_gwt<<<(128 * 64 + 255) / 256, 256, 0, stream>>>(greW, gWt);

    dim3 ggrid((NN + 127) / 128, FF / 64);
    // positive hops
    k_gemm16<<<ggrid, 256, 0, stream>>>(out0h, Wtp, Cb16, NN);
    k_agg<<<NN, 640, 0, stream>>>(Cb16, rowptr, colsrc, normp, disp, bpos, h1);
    k_gemm16<<<ggrid, 256, 0, stream>>>(h1, Wtp, Cb16, NN);
    k_agg<<<NN, 640, 0, stream>>>(Cb16, rowptr, colsrc, normp, disp, bpos, h2);
    k_gemm16<<<ggrid, 256, 0, stream>>>(h2, Wtp, Cb16, NN);
    k_agg<<<NN, 640, 0, stream>>>(Cb16, rowptr, colsrc, normp, disp, bpos, h3);
    // negative branch
    k_gemm16<<<ggrid, 256, 0, stream>>>(out0h, Wtn, Cb16, NN);
    k_agg<<<NN, 640, 0, stream>>>(Cb16, rowptr, colsrc, normn, disn, bneg, hneg);
    // GReTo channel mix (MFMA) + psi accumulation + relu
    k_greto2<<<(NR + 127) / 128, 256, 0, stream>>>(h1, h2, h3, hneg, psib, gWt, greb, Cbuf);
    // final gated TCN
    k_tcn2<<<2500, 256, 0, stream>>>(Cbuf, wt, tc2b1, tc2b2, out);
}

// Round 12
// 738.176 us; speedup vs baseline: 2.0513x; 1.1183x over previous
//
#include <hip/hip_runtime.h>
#include <math.h>

#define NN   10000   // nodes
#define NE   160000  // edges
#define CCH  64      // in/out channels
#define TIN  12      // input time steps
#define HCH  64      // hidden channels
#define TSP  10      // T - 2
#define FF   640     // H * TSP
#define TOUT 8       // TSP - 2
#define NR   (NN * TSP)    // 100000 rows for tcn1 / GCN / greto
#define NR2  (NN * TOUT)   // 80000 rows for tcn2

// GCN feature ordering: f' = t*64 + h (channel-contiguous rows)

typedef _Float16 f16;
typedef _Float16 f16x8 __attribute__((ext_vector_type(8)));
typedef float f32x4 __attribute__((ext_vector_type(4)));

// ---------------- x transpose: xT[n][t][c] = (f16)x[n][c][t] ----------------
__global__ __launch_bounds__(256) void k_xT(const float* __restrict__ x, f16* __restrict__ xT)
{
    __shared__ float xs[4][CCH * TIN];
    int node0 = blockIdx.x * 4;
    for (int i = threadIdx.x; i < 4 * CCH * TIN; i += 256) {
        int nn = i / (CCH * TIN), off = i % (CCH * TIN);
        int g = node0 + nn;
        xs[nn][off] = (g < NN) ? x[(size_t)g * CCH * TIN + off] : 0.f;
    }
    __syncthreads();
    for (int i = threadIdx.x; i < 4 * CCH * TIN; i += 256) {
        int nn = i / (CCH * TIN), off = i % (CCH * TIN);
        int t = off >> 6, c = off & 63;
        int g = node0 + nn;
        if (g < NN) xT[(size_t)g * (CCH * TIN) + off] = (f16)xs[nn][c * TIN + t];
    }
}

// ---------------- conv weights -> Bw[o][k*64+ci] f16 ------------------------
// o<64: filter1 (tanh), o>=64: filter2 (sigmoid); src[cout][cin][k]
__global__ void k_wconv(const float* __restrict__ w1, const float* __restrict__ w2,
                        f16* __restrict__ dst)
{
    int tid = blockIdx.x * 256 + threadIdx.x;
    if (tid >= 128 * 192) return;
    int o = tid / 192, j = tid % 192;
    int k = j >> 6, ci = j & 63;
    const float* src = (o < 64) ? w1 : w2;
    dst[tid] = (f16)src[((o & 63) * 64 + ci) * 3 + k];
}

// ---------------- TCN as direct GEMM (sliding-window A) ---------------------
// A row r: contiguous 192 f16 at Abuf + n*LDN + t*64;  Bw [128][192]
// gate: out = tanh(G[:,0:64]+b1) * sigmoid(G[:,64:128]+b2)
__global__ __launch_bounds__(256) void k_tcn1g(const f16* __restrict__ A,   // xT [NN][768]
                                               const f16* __restrict__ Bw,
                                               const float* __restrict__ b1,
                                               const float* __restrict__ b2,
                                               f16* __restrict__ out)       // [NR][64] = f' order
{
    int tid = threadIdx.x;
    int w = tid >> 6, l = tid & 63;
    int row0 = blockIdx.x * 128 + w * 32;
    int lrow = l & 15, lk = (l >> 4) * 8;

    size_t abase[2];
#pragma unroll
    for (int m = 0; m < 2; ++m) {
        int rr = row0 + m * 16 + lrow;
        int rc = (rr < NR) ? rr : NR - 1;
        int n = rc / 10, t = rc - n * 10;
        abase[m] = (size_t)n * 768 + t * 64 + lk;
    }
    f32x4 acc[2][8];
#pragma unroll
    for (int m = 0; m < 2; ++m)
#pragma unroll
        for (int n = 0; n < 8; ++n)
            acc[m][n] = (f32x4){0.f, 0.f, 0.f, 0.f};

#pragma unroll
    for (int ks = 0; ks < 6; ++ks) {
        f16x8 af[2], bf[8];
#pragma unroll
        for (int m = 0; m < 2; ++m)
            af[m] = *(const f16x8*)&A[abase[m] + ks * 32];
#pragma unroll
        for (int n = 0; n < 8; ++n)
            bf[n] = *(const f16x8*)&Bw[(n * 16 + lrow) * 192 + ks * 32 + lk];
#pragma unroll
        for (int m = 0; m < 2; ++m)
#pragma unroll
            for (int n = 0; n < 8; ++n)
                acc[m][n] = __builtin_amdgcn_mfma_f32_16x16x32_f16(af[m], bf[n], acc[m][n], 0, 0, 0);
    }
    int og = (l >> 4) * 4;
#pragma unroll
    for (int m = 0; m < 2; ++m) {
#pragma unroll
        for (int n = 0; n < 4; ++n) {
            int h = n * 16 + lrow;
            float bb1 = b1[h], bb2 = b2[h];
#pragma unroll
            for (int rr = 0; rr < 4; ++rr) {
                int R = row0 + m * 16 + og + rr;
                if (R < NR) {
                    float g1 = acc[m][n][rr] + bb1;
                    float g2 = acc[m][n + 4][rr] + bb2;
                    float e = __expf(2.f * g1);
                    float th = 1.f - 2.f / (e + 1.f);
                    float sg = 1.f / (1.f + __expf(-g2));
                    out[(size_t)R * 64 + h] = (f16)(th * sg);
                }
            }
        }
    }
}

// TCN2: A = Gbuf [NN][640] f16, rows r=n*8+t, slice at n*640+t*64; f32 out [N,64,8]
__global__ __launch_bounds__(256) void k_tcn2g(const f16* __restrict__ A,
                                               const f16* __restrict__ Bw,
                                               const float* __restrict__ b1,
                                               const float* __restrict__ b2,
                                               float* __restrict__ out)
{
    int tid = threadIdx.x;
    int w = tid >> 6, l = tid & 63;
    int row0 = blockIdx.x * 128 + w * 32;
    int lrow = l & 15, lk = (l >> 4) * 8;

    size_t abase[2];
#pragma unroll
    for (int m = 0; m < 2; ++m) {
        int rr = row0 + m * 16 + lrow;
        int rc = (rr < NR2) ? rr : NR2 - 1;
        int n = rc >> 3, t = rc & 7;
        abase[m] = (size_t)n * FF + t * 64 + lk;
    }
    f32x4 acc[2][8];
#pragma unroll
    for (int m = 0; m < 2; ++m)
#pragma unroll
        for (int n = 0; n < 8; ++n)
            acc[m][n] = (f32x4){0.f, 0.f, 0.f, 0.f};

#pragma unroll
    for (int ks = 0; ks < 6; ++ks) {
        f16x8 af[2], bf[8];
#pragma unroll
        for (int m = 0; m < 2; ++m)
            af[m] = *(const f16x8*)&A[abase[m] + ks * 32];
#pragma unroll
        for (int n = 0; n < 8; ++n)
            bf[n] = *(const f16x8*)&Bw[(n * 16 + lrow) * 192 + ks * 32 + lk];
#pragma unroll
        for (int m = 0; m < 2; ++m)
#pragma unroll
            for (int n = 0; n < 8; ++n)
                acc[m][n] = __builtin_amdgcn_mfma_f32_16x16x32_f16(af[m], bf[n], acc[m][n], 0, 0, 0);
    }
    int og = (l >> 4) * 4;
#pragma unroll
    for (int m = 0; m < 2; ++m) {
#pragma unroll
        for (int n = 0; n < 4; ++n) {
            int c = n * 16 + lrow;
            float bb1 = b1[c], bb2 = b2[c];
#pragma unroll
            for (int rr = 0; rr < 4; ++rr) {
                int R = row0 + m * 16 + og + rr;
                if (R < NR2) {
                    float g1 = acc[m][n][rr] + bb1;
                    float g2 = acc[m][n + 4][rr] + bb2;
                    float e = __expf(2.f * g1);
                    float th = 1.f - 2.f / (e + 1.f);
                    float sg = 1.f / (1.f + __expf(-g2));
                    int n2 = R >> 3, t2 = R & 7;
                    out[(size_t)n2 * (CCH * TOUT) + c * TOUT + t2] = th * sg;
                }
            }
        }
    }
}

// ---------------- psi MLP ---------------------------------------------------
__global__ void k_psi(const float* __restrict__ ND, const float* __restrict__ W1,
                      const float* __restrict__ b1, const float* __restrict__ W2,
                      const float* __restrict__ b2, float* __restrict__ psi)
{
    int n = blockIdx.x * blockDim.x + threadIdx.x;
    if (n >= NN) return;
    float d0 = ND[n * 3], d1 = ND[n * 3 + 1], d2 = ND[n * 3 + 2];
    float o0 = b2[0], o1 = b2[1], o2 = b2[2];
    for (int j = 0; j < 64; ++j) {
        float hv = d0 * W1[j] + d1 * W1[64 + j] + d2 * W1[128 + j] + b1[j];
        hv = fmaxf(hv, 0.f);
        o0 += hv * W2[j * 3 + 0];
        o1 += hv * W2[j * 3 + 1];
        o2 += hv * W2[j * 3 + 2];
    }
    psi[n * 3 + 0] = o0; psi[n * 3 + 1] = o1; psi[n * 3 + 2] = o2;
}

// ---------------- degree / counts -------------------------------------------
__global__ void k_deg(const int* __restrict__ ei, const float* __restrict__ ea,
                      int* __restrict__ cnt, float* __restrict__ degp, float* __restrict__ degn)
{
    int e = blockIdx.x * blockDim.x + threadIdx.x;
    if (e >= NE) return;
    int d = ei[NE + e];
    atomicAdd(&cnt[d], 1);
    atomicAdd(&degp[d], ea[e * 2 + 0] + 1.f);
    atomicAdd(&degn[d], ea[e * 2 + 1] + 1.f);
}

__global__ void k_dis(const float* __restrict__ degp, const float* __restrict__ degn,
                      float* __restrict__ disp, float* __restrict__ disn)
{
    int n = blockIdx.x * blockDim.x + threadIdx.x;
    if (n >= NN) return;
    disp[n] = 1.f / sqrtf(degp[n] + 1.f);
    disn[n] = 1.f / sqrtf(degn[n] + 1.f);
}

// ---------------- exclusive scan --------------------------------------------
__global__ __launch_bounds__(1024) void k_scan(const int* __restrict__ cnt, int* __restrict__ rowptr)
{
    __shared__ int buf[1024];
    __shared__ int carry;
    if (threadIdx.x == 0) carry = 0;
    __syncthreads();
    for (int base = 0; base < NN; base += 1024) {
        int i = base + threadIdx.x;
        int v = (i < NN) ? cnt[i] : 0;
        buf[threadIdx.x] = v;
        __syncthreads();
        for (int off = 1; off < 1024; off <<= 1) {
            int t = (threadIdx.x >= (unsigned)off) ? buf[threadIdx.x - off] : 0;
            __syncthreads();
            buf[threadIdx.x] += t;
            __syncthreads();
        }
        if (i < NN) rowptr[i] = carry + buf[threadIdx.x] - v;
        __syncthreads();
        if (threadIdx.x == 0) carry += buf[1023];
        __syncthreads();
    }
    if (threadIdx.x == 0) rowptr[NN] = carry;
}

// ---------------- CSR fill ---------------------------------------------------
__global__ void k_fill(const int* __restrict__ ei, const float* __restrict__ ea,
                       const int* __restrict__ rowptr, int* __restrict__ cursor,
                       const float* __restrict__ disp, const float* __restrict__ disn,
                       int* __restrict__ colsrc, float* __restrict__ normp, float* __restrict__ normn)
{
    int e = blockIdx.x * blockDim.x + threadIdx.x;
    if (e >= NE) return;
    int s = ei[e], d = ei[NE + e];
    int slot = atomicAdd(&cursor[d], 1);
    int idx = rowptr[d] + slot;
    colsrc[idx] = s;
    normp[idx] = disp[s] * (ea[e * 2 + 0] + 1.f) * disp[d];
    normn[idx] = disn[s] * (ea[e * 2 + 1] + 1.f) * disn[d];
}

// ---------------- W transpose+cast: Wt0[n][k] = (f16)W[k][n] ----------------
__global__ __launch_bounds__(256) void k_wsplit(const float* __restrict__ W, f16* __restrict__ Wt)
{
    __shared__ float t[32][33];
    int bx = blockIdx.x * 32;
    int by = blockIdx.y * 32;
    int tx = threadIdx.x & 31, ty = threadIdx.x >> 5;
#pragma unroll
    for (int j = 0; j < 4; ++j)
        t[ty + j * 8][tx] = W[(size_t)(bx + ty + j * 8) * 640 + by + tx];
    __syncthreads();
#pragma unroll
    for (int j = 0; j < 4; ++j)
        Wt[(size_t)(by + ty + j * 8) * 640 + bx + tx] = (f16)t[tx][ty + j * 8];
}

// ---------------- permute rows+cols to f' order -----------------------------
__global__ __launch_bounds__(640) void k_perm(const f16* __restrict__ Wt0, f16* __restrict__ Wt)
{
    __shared__ f16 row[FF];
    int np = blockIdx.x;
    int n = (np & 63) * 10 + (np >> 6);
    int tid = threadIdx.x;
    row[tid] = Wt0[(size_t)n * FF + tid];
    __syncthreads();
    int k = (tid & 63) * 10 + (tid >> 6);
    Wt[(size_t)np * FF + tid] = row[k];
}

// ---------------- gW transpose: gWt[d][c] = (f16)gW[c][d] -------------------
__global__ void k_gwt(const float* __restrict__ gW, f16* __restrict__ gWt)
{
    int tid = blockIdx.x * 256 + threadIdx.x;
    if (tid >= 128 * 64) return;
    int c = tid >> 6, d = tid & 63;
    gWt[d * 128 + c] = (f16)gW[tid];
}

// ---------------- f16 MFMA GEMM: C[M,640] = A[M,640] @ Bt^T (f16 out) -------
__global__ __launch_bounds__(256) void k_gemm16(const f16* __restrict__ A,
                                                const f16* __restrict__ Bt,
                                                f16* __restrict__ C, int M)
{
    __shared__ f16 As[128][40];
    __shared__ f16 Bs[64][40];
    int tid = threadIdx.x;
    int row0 = blockIdx.x * 128;
    int col0 = blockIdx.y * 64;
    int w = tid >> 6, l = tid & 63;
    int wr = (w >> 1) * 64;
    int wc = (w & 1) * 32;
    int lrow = l & 15;
    int lk = (l >> 4) * 8;
    int srow = tid >> 2;
    int sseg = (tid & 3) * 8;

    f32x4 acc[4][2];
#pragma unroll
    for (int m = 0; m < 4; ++m)
#pragma unroll
        for (int n = 0; n < 2; ++n)
            acc[m][n] = (f32x4){0.f, 0.f, 0.f, 0.f};

    for (int k0 = 0; k0 < FF; k0 += 32) {
        f16x8 a0 = {}, a1 = {};
        int r0 = row0 + srow, r1 = row0 + srow + 64;
        if (r0 < M) a0 = *(const f16x8*)&A[(size_t)r0 * FF + k0 + sseg];
        if (r1 < M) a1 = *(const f16x8*)&A[(size_t)r1 * FF + k0 + sseg];
        f16x8 b0 = *(const f16x8*)&Bt[(size_t)(col0 + srow) * FF + k0 + sseg];
        __syncthreads();
        *(f16x8*)&As[srow][sseg]      = a0;
        *(f16x8*)&As[srow + 64][sseg] = a1;
        *(f16x8*)&Bs[srow][sseg]      = b0;
        __syncthreads();
        f16x8 af[4], bf[2];
#pragma unroll
        for (int m = 0; m < 4; ++m)
            af[m] = *(const f16x8*)&As[wr + m * 16 + lrow][lk];
#pragma unroll
        for (int n = 0; n < 2; ++n)
            bf[n] = *(const f16x8*)&Bs[wc + n * 16 + lrow][lk];
#pragma unroll
        for (int m = 0; m < 4; ++m)
#pragma unroll
            for (int n = 0; n < 2; ++n)
                acc[m][n] = __builtin_amdgcn_mfma_f32_16x16x32_f16(af[m], bf[n], acc[m][n], 0, 0, 0);
    }
    int orow = (l >> 4) * 4;
#pragma unroll
    for (int m = 0; m < 4; ++m) {
#pragma unroll
        for (int r = 0; r < 4; ++r) {
            int rr = row0 + wr + m * 16 + orow + r;
            if (rr < M) {
#pragma unroll
                for (int n = 0; n < 2; ++n)
                    C[(size_t)rr * FF + col0 + wc + n * 16 + lrow] = (f16)acc[m][n][r];
            }
        }
    }
}

// ---------------- GCN aggregate (f' order; bias permuted inline) ------------
__global__ void k_agg(const f16* __restrict__ hsrc, const int* __restrict__ rowptr,
                      const int* __restrict__ colsrc, const float* __restrict__ enorm,
                      const float* __restrict__ dis, const float* __restrict__ bias,
                      f16* __restrict__ hout)
{
    int d = blockIdx.x;
    int f = threadIdx.x;            // f' = t*64 + h
    float selfw = dis[d] * dis[d];
    float v = selfw * (float)hsrc[(size_t)d * FF + f];
    int beg = rowptr[d], end = rowptr[d + 1];
    for (int idx = beg; idx < end; ++idx) {
        int s = colsrc[idx];
        float w = enorm[idx];
        v += w * (float)hsrc[(size_t)s * FF + f];
    }
    v += bias[(f & 63) * 10 + (f >> 6)];
    v = fmaxf(v, 0.f);
    hout[(size_t)d * FF + f] = (f16)v;
}

// ---------------- GReTo mix as MFMA GEMM (f16 out) --------------------------
__global__ __launch_bounds__(256) void k_greto2(const f16* __restrict__ h1,
                        const f16* __restrict__ h2, const f16* __restrict__ h3,
                        const f16* __restrict__ hneg, const float* __restrict__ psi,
                        const f16* __restrict__ gWt, const float* __restrict__ gb,
                        f16* __restrict__ out)
{
    __shared__ f16 As[128][132];
    __shared__ f16 Bs[64][132];
    int tid = threadIdx.x;
    int row0 = blockIdx.x * 128;

    for (int cb = tid; cb < 1024; cb += 256) {
        int d = cb >> 4, seg = (cb & 15) * 8;
        *(f16x8*)&Bs[d][seg] = *(const f16x8*)&gWt[d * 128 + seg];
    }
    int lr = tid >> 1, side = tid & 1;
    int r = row0 + lr;
    if (r < NR) {
        int n = r / 10, t = r - (r / 10) * 10;
        size_t base = (size_t)n * FF + t * 64;
        if (side == 0) {
            float p0 = psi[n * 3], p1 = psi[n * 3 + 1], p2 = psi[n * 3 + 2];
#pragma unroll
            for (int i = 0; i < 8; ++i) {
                f16x8 a = *(const f16x8*)&h1[base + i * 8];
                f16x8 b = *(const f16x8*)&h2[base + i * 8];
                f16x8 c = *(const f16x8*)&h3[base + i * 8];
                f16x8 o;
#pragma unroll
                for (int j = 0; j < 8; ++j)
                    o[j] = (f16)(p0 * (float)a[j] + p1 * (float)b[j] + p2 * (float)c[j]);
                *(f16x8*)&As[lr][i * 8] = o;
            }
        } else {
#pragma unroll
            for (int i = 0; i < 8; ++i)
                *(f16x8*)&As[lr][64 + i * 8] = *(const f16x8*)&hneg[base + i * 8];
        }
    } else {
        f16x8 z = {};
#pragma unroll
        for (int i = 0; i < 8; ++i)
            *(f16x8*)&As[lr][side * 64 + i * 8] = z;
    }
    __syncthreads();

    int w = tid >> 6, l = tid & 63;
    int wr = w * 32;
    int lrow = l & 15;
    int lk = (l >> 4) * 8;
    f32x4 acc[2][4];
#pragma unroll
    for (int m = 0; m < 2; ++m)
#pragma unroll
        for (int n = 0; n < 4; ++n)
            acc[m][n] = (f32x4){0.f, 0.f, 0.f, 0.f};
#pragma unroll
    for (int ks = 0; ks < 4; ++ks) {
        f16x8 af[2], bf[4];
#pragma unroll
        for (int m = 0; m < 2; ++m)
            af[m] = *(const f16x8*)&As[wr + m * 16 + lrow][ks * 32 + lk];
#pragma unroll
        for (int n = 0; n < 4; ++n)
            bf[n] = *(const f16x8*)&Bs[n * 16 + lrow][ks * 32 + lk];
#pragma unroll
        for (int m = 0; m < 2; ++m)
#pragma unroll
            for (int n = 0; n < 4; ++n)
                acc[m][n] = __builtin_amdgcn_mfma_f32_16x16x32_f16(af[m], bf[n], acc[m][n], 0, 0, 0);
    }
    int orow = (l >> 4) * 4;
#pragma unroll
    for (int m = 0; m < 2; ++m) {
#pragma unroll
        for (int rr = 0; rr < 4; ++rr) {
            int ro = row0 + wr + m * 16 + orow + rr;
            if (ro < NR) {
#pragma unroll
                for (int n = 0; n < 4; ++n) {
                    int col = n * 16 + lrow;
                    out[(size_t)ro * 64 + col] = (f16)fmaxf(acc[m][n][rr] + gb[col], 0.f);
                }
            }
        }
    }
}

extern "C" void kernel_launch(void* const* d_in, const int* in_sizes, int n_in,
                              void* d_out, int out_size, void* d_ws, size_t ws_size,
                              hipStream_t stream)
{
    const float* x     = (const float*)d_in[0];
    const int*   ei    = (const int*)  d_in[1];
    const float* ea    = (const float*)d_in[2];
    const float* ndt   = (const float*)d_in[3];
    const float* tc1w1 = (const float*)d_in[4];
    const float* tc1b1 = (const float*)d_in[5];
    const float* tc1w2 = (const float*)d_in[6];
    const float* tc1b2 = (const float*)d_in[7];
    const float* Wpos  = (const float*)d_in[8];
    const float* bpos  = (const float*)d_in[9];
    const float* Wneg  = (const float*)d_in[10];
    const float* bneg  = (const float*)d_in[11];
    const float* greW  = (const float*)d_in[12];
    const float* greb  = (const float*)d_in[13];
    const float* psiW1 = (const float*)d_in[14];
    const float* psib1 = (const float*)d_in[15];
    const float* psiW2 = (const float*)d_in[16];
    const float* psib2 = (const float*)d_in[17];
    const float* tc2w1 = (const float*)d_in[18];
    const float* tc2b1 = (const float*)d_in[19];
    const float* tc2w2 = (const float*)d_in[20];
    const float* tc2b2 = (const float*)d_in[21];
    float* out = (float*)d_out;

    char* p = (char*)d_ws;
    f16*   xT    = (f16*)p;   p += (size_t)NN * CCH * TIN * 2;
    f16*   out0h = (f16*)p;   p += (size_t)NN * FF * 2;
    f16*   h1    = (f16*)p;   p += (size_t)NN * FF * 2;
    f16*   h2    = (f16*)p;   p += (size_t)NN * FF * 2;
    f16*   h3    = (f16*)p;   p += (size_t)NN * FF * 2;
    f16*   hneg  = (f16*)p;   p += (size_t)NN * FF * 2;
    f16*   Cb16  = (f16*)p;   p += (size_t)NN * FF * 2;
    f16*   Gbuf  = (f16*)p;   p += (size_t)NN * FF * 2;
    f16*   Wtp   = (f16*)p;   p += (size_t)FF * FF * 2;
    f16*   Wtn   = (f16*)p;   p += (size_t)FF * FF * 2;
    f16*   Wtmp  = (f16*)p;   p += (size_t)FF * FF * 2;
    f16*   gWt   = (f16*)p;   p += (size_t)128 * 64 * 2;
    f16*   Bw1   = (f16*)p;   p += (size_t)128 * 192 * 2;
    f16*   Bw2   = (f16*)p;   p += (size_t)128 * 192 * 2;
    float* psib  = (float*)p; p += (size_t)NN * 3 * 4;
    float* degp  = (float*)p; p += (size_t)NN * 4;
    float* degn  = (float*)p; p += (size_t)NN * 4;
    float* disp  = (float*)p; p += (size_t)NN * 4;
    float* disn  = (float*)p; p += (size_t)NN * 4;
    float* normp = (float*)p; p += (size_t)NE * 4;
    float* normn = (float*)p; p += (size_t)NE * 4;
    int* cnt     = (int*)p;   p += (size_t)NN * 4;
    int* rowptr  = (int*)p;   p += (size_t)(NN + 1) * 4;
    int* cursor  = (int*)p;   p += (size_t)NN * 4;
    int* colsrc  = (int*)p;   p += (size_t)NE * 4;

    (void)hipMemsetAsync(cnt, 0, NN * 4, stream);
    (void)hipMemsetAsync(cursor, 0, NN * 4, stream);
    (void)hipMemsetAsync(degp, 0, NN * 4, stream);
    (void)hipMemsetAsync(degn, 0, NN * 4, stream);

    k_xT<<<2500, 256, 0, stream>>>(x, xT);
    k_wconv<<<(128 * 192 + 255) / 256, 256, 0, stream>>>(tc1w1, tc1w2, Bw1);
    k_wconv<<<(128 * 192 + 255) / 256, 256, 0, stream>>>(tc2w1, tc2w2, Bw2);
    k_tcn1g<<<(NR + 127) / 128, 256, 0, stream>>>(xT, Bw1, tc1b1, tc1b2, out0h);
    k_psi<<<(NN + 255) / 256, 256, 0, stream>>>(ndt, psiW1, psib1, psiW2, psib2, psib);
    k_deg<<<(NE + 255) / 256, 256, 0, stream>>>(ei, ea, cnt, degp, degn);
    k_dis<<<(NN + 255) / 256, 256, 0, stream>>>(degp, degn, disp, disn);
    k_scan<<<1, 1024, 0, stream>>>(cnt, rowptr);
    k_fill<<<(NE + 255) / 256, 256, 0, stream>>>(ei, ea, rowptr, cursor, disp, disn,
                                                 colsrc, normp, normn);
    dim3 wgrid(20, 20);
    k_wsplit<<<wgrid, 256, 0, stream>>>(Wpos, Wtmp);
    k_perm<<<FF, 640, 0, stream>>>(Wtmp, Wtp);
    k_wsplit<<<wgrid, 256, 0, stream>>>(Wneg, Wtmp);
    k_perm<<<FF, 640, 0, stream>>>(Wtmp, Wtn);
    k_gwt<<<(128 * 64 + 255) / 256, 256, 0, stream>>>(greW, gWt);

    dim3 ggrid((NN + 127) / 128, FF / 64);
    // positive hops
    k_gemm16<<<ggrid, 256, 0, stream>>>(out0h, Wtp, Cb16, NN);
    k_agg<<<NN, 640, 0, stream>>>(Cb16, rowptr, colsrc, normp, disp, bpos, h1);
    k_gemm16<<<ggrid, 256, 0, stream>>>(h1, Wtp, Cb16, NN);
    k_agg<<<NN, 640, 0, stream>>>(Cb16, rowptr, colsrc, normp, disp, bpos, h2);
    k_gemm16<<<ggrid, 256, 0, stream>>>(h2, Wtp, Cb16, NN);
    k_agg<<<NN, 640, 0, stream>>>(Cb16, rowptr, colsrc, normp, disp, bpos, h3);
    // negative branch
    k_gemm16<<<ggrid, 256, 0, stream>>>(out0h, Wtn, Cb16, NN);
    k_agg<<<NN, 640, 0, stream>>>(Cb16, rowptr, colsrc, normn, disn, bneg, hneg);
    // GReTo channel mix (MFMA) + psi accumulation + relu -> f16
    k_greto2<<<(NR + 127) / 128, 256, 0, stream>>>(h1, h2, h3, hneg, psib, gWt, greb, Gbuf);
    // final gated TCN as direct GEMM
    k_tcn2g<<<(NR2 + 127) / 128, 256, 0, stream>>>(Gbuf, Bw2, tc2b1, tc2b2, out);
}

// Round 13
// 464.314 us; speedup vs baseline: 3.2613x; 1.5898x over previous
//
#include <hip/hip_runtime.h>
#include <math.h>

#define NN   10000   // nodes
#define NE   160000  // edges
#define CCH  64      // in/out channels
#define TIN  12      // input time steps
#define HCH  64      // hidden channels
#define TSP  10      // T - 2
#define FF   640     // H * TSP
#define TOUT 8       // TSP - 2
#define NR   (NN * TSP)    // 100000 rows for tcn1 / GCN / greto
#define NR2  (NN * TOUT)   // 80000 rows for tcn2

// GCN feature ordering: f' = t*64 + h (channel-contiguous rows)

typedef _Float16 f16;
typedef _Float16 f16x2 __attribute__((ext_vector_type(2)));
typedef _Float16 f16x8 __attribute__((ext_vector_type(8)));
typedef float f32x4 __attribute__((ext_vector_type(4)));

// ---------------- x transpose: xT[n][t][c] = (f16)x[n][c][t] ----------------
__global__ __launch_bounds__(256) void k_xT(const float* __restrict__ x, f16* __restrict__ xT)
{
    __shared__ float xs[4][CCH * TIN];
    int node0 = blockIdx.x * 4;
    for (int i = threadIdx.x; i < 4 * CCH * TIN; i += 256) {
        int nn = i / (CCH * TIN), off = i % (CCH * TIN);
        int g = node0 + nn;
        xs[nn][off] = (g < NN) ? x[(size_t)g * CCH * TIN + off] : 0.f;
    }
    __syncthreads();
    for (int i = threadIdx.x; i < 4 * CCH * TIN; i += 256) {
        int nn = i / (CCH * TIN), off = i % (CCH * TIN);
        int t = off >> 6, c = off & 63;
        int g = node0 + nn;
        if (g < NN) xT[(size_t)g * (CCH * TIN) + off] = (f16)xs[nn][c * TIN + t];
    }
}

// ---------------- conv weights -> Bw[o][k*64+ci] f16 ------------------------
__global__ void k_wconv(const float* __restrict__ w1, const float* __restrict__ w2,
                        f16* __restrict__ dst)
{
    int tid = blockIdx.x * 256 + threadIdx.x;
    if (tid >= 128 * 192) return;
    int o = tid / 192, j = tid % 192;
    int k = j >> 6, ci = j & 63;
    const float* src = (o < 64) ? w1 : w2;
    dst[tid] = (f16)src[((o & 63) * 64 + ci) * 3 + k];
}

// ---------------- TCN1 as direct GEMM (sliding-window A) --------------------
__global__ __launch_bounds__(256) void k_tcn1g(const f16* __restrict__ A,   // xT [NN][768]
                                               const f16* __restrict__ Bw,
                                               const float* __restrict__ b1,
                                               const float* __restrict__ b2,
                                               f16* __restrict__ out)       // [NR][64] = f' order
{
    int tid = threadIdx.x;
    int w = tid >> 6, l = tid & 63;
    int row0 = blockIdx.x * 128 + w * 32;
    int lrow = l & 15, lk = (l >> 4) * 8;

    size_t abase[2];
#pragma unroll
    for (int m = 0; m < 2; ++m) {
        int rr = row0 + m * 16 + lrow;
        int rc = (rr < NR) ? rr : NR - 1;
        int n = rc / 10, t = rc - n * 10;
        abase[m] = (size_t)n * 768 + t * 64 + lk;
    }
    f32x4 acc[2][8];
#pragma unroll
    for (int m = 0; m < 2; ++m)
#pragma unroll
        for (int n = 0; n < 8; ++n)
            acc[m][n] = (f32x4){0.f, 0.f, 0.f, 0.f};

#pragma unroll
    for (int ks = 0; ks < 6; ++ks) {
        f16x8 af[2], bf[8];
#pragma unroll
        for (int m = 0; m < 2; ++m)
            af[m] = *(const f16x8*)&A[abase[m] + ks * 32];
#pragma unroll
        for (int n = 0; n < 8; ++n)
            bf[n] = *(const f16x8*)&Bw[(n * 16 + lrow) * 192 + ks * 32 + lk];
#pragma unroll
        for (int m = 0; m < 2; ++m)
#pragma unroll
            for (int n = 0; n < 8; ++n)
                acc[m][n] = __builtin_amdgcn_mfma_f32_16x16x32_f16(af[m], bf[n], acc[m][n], 0, 0, 0);
    }
    int og = (l >> 4) * 4;
#pragma unroll
    for (int m = 0; m < 2; ++m) {
#pragma unroll
        for (int n = 0; n < 4; ++n) {
            int h = n * 16 + lrow;
            float bb1 = b1[h], bb2 = b2[h];
#pragma unroll
            for (int rr = 0; rr < 4; ++rr) {
                int R = row0 + m * 16 + og + rr;
                if (R < NR) {
                    float g1 = acc[m][n][rr] + bb1;
                    float g2 = acc[m][n + 4][rr] + bb2;
                    float e = __expf(2.f * g1);
                    float th = 1.f - 2.f / (e + 1.f);
                    float sg = 1.f / (1.f + __expf(-g2));
                    out[(size_t)R * 64 + h] = (f16)(th * sg);
                }
            }
        }
    }
}

// TCN2: A = Gbuf [NN][640] f16, rows r=n*8+t, slice at n*640+t*64; f32 out [N,64,8]
__global__ __launch_bounds__(256) void k_tcn2g(const f16* __restrict__ A,
                                               const f16* __restrict__ Bw,
                                               const float* __restrict__ b1,
                                               const float* __restrict__ b2,
                                               float* __restrict__ out)
{
    int tid = threadIdx.x;
    int w = tid >> 6, l = tid & 63;
    int row0 = blockIdx.x * 128 + w * 32;
    int lrow = l & 15, lk = (l >> 4) * 8;

    size_t abase[2];
#pragma unroll
    for (int m = 0; m < 2; ++m) {
        int rr = row0 + m * 16 + lrow;
        int rc = (rr < NR2) ? rr : NR2 - 1;
        int n = rc >> 3, t = rc & 7;
        abase[m] = (size_t)n * FF + t * 64 + lk;
    }
    f32x4 acc[2][8];
#pragma unroll
    for (int m = 0; m < 2; ++m)
#pragma unroll
        for (int n = 0; n < 8; ++n)
            acc[m][n] = (f32x4){0.f, 0.f, 0.f, 0.f};

#pragma unroll
    for (int ks = 0; ks < 6; ++ks) {
        f16x8 af[2], bf[8];
#pragma unroll
        for (int m = 0; m < 2; ++m)
            af[m] = *(const f16x8*)&A[abase[m] + ks * 32];
#pragma unroll
        for (int n = 0; n < 8; ++n)
            bf[n] = *(const f16x8*)&Bw[(n * 16 + lrow) * 192 + ks * 32 + lk];
#pragma unroll
        for (int m = 0; m < 2; ++m)
#pragma unroll
            for (int n = 0; n < 8; ++n)
                acc[m][n] = __builtin_amdgcn_mfma_f32_16x16x32_f16(af[m], bf[n], acc[m][n], 0, 0, 0);
    }
    int og = (l >> 4) * 4;
#pragma unroll
    for (int m = 0; m < 2; ++m) {
#pragma unroll
        for (int n = 0; n < 4; ++n) {
            int c = n * 16 + lrow;
            float bb1 = b1[c], bb2 = b2[c];
#pragma unroll
            for (int rr = 0; rr < 4; ++rr) {
                int R = row0 + m * 16 + og + rr;
                if (R < NR2) {
                    float g1 = acc[m][n][rr] + bb1;
                    float g2 = acc[m][n + 4][rr] + bb2;
                    float e = __expf(2.f * g1);
                    float th = 1.f - 2.f / (e + 1.f);
                    float sg = 1.f / (1.f + __expf(-g2));
                    int n2 = R >> 3, t2 = R & 7;
                    out[(size_t)n2 * (CCH * TOUT) + c * TOUT + t2] = th * sg;
                }
            }
        }
    }
}

// ---------------- psi MLP ---------------------------------------------------
__global__ void k_psi(const float* __restrict__ ND, const float* __restrict__ W1,
                      const float* __restrict__ b1, const float* __restrict__ W2,
                      const float* __restrict__ b2, float* __restrict__ psi)
{
    int n = blockIdx.x * blockDim.x + threadIdx.x;
    if (n >= NN) return;
    float d0 = ND[n * 3], d1 = ND[n * 3 + 1], d2 = ND[n * 3 + 2];
    float o0 = b2[0], o1 = b2[1], o2 = b2[2];
    for (int j = 0; j < 64; ++j) {
        float hv = d0 * W1[j] + d1 * W1[64 + j] + d2 * W1[128 + j] + b1[j];
        hv = fmaxf(hv, 0.f);
        o0 += hv * W2[j * 3 + 0];
        o1 += hv * W2[j * 3 + 1];
        o2 += hv * W2[j * 3 + 2];
    }
    psi[n * 3 + 0] = o0; psi[n * 3 + 1] = o1; psi[n * 3 + 2] = o2;
}

// ---------------- degree / counts -------------------------------------------
__global__ void k_deg(const int* __restrict__ ei, const float* __restrict__ ea,
                      int* __restrict__ cnt, float* __restrict__ degp, float* __restrict__ degn)
{
    int e = blockIdx.x * blockDim.x + threadIdx.x;
    if (e >= NE) return;
    int d = ei[NE + e];
    atomicAdd(&cnt[d], 1);
    atomicAdd(&degp[d], ea[e * 2 + 0] + 1.f);
    atomicAdd(&degn[d], ea[e * 2 + 1] + 1.f);
}

__global__ void k_dis(const float* __restrict__ degp, const float* __restrict__ degn,
                      float* __restrict__ disp, float* __restrict__ disn)
{
    int n = blockIdx.x * blockDim.x + threadIdx.x;
    if (n >= NN) return;
    disp[n] = 1.f / sqrtf(degp[n] + 1.f);
    disn[n] = 1.f / sqrtf(degn[n] + 1.f);
}

// ---------------- exclusive scan --------------------------------------------
__global__ __launch_bounds__(1024) void k_scan(const int* __restrict__ cnt, int* __restrict__ rowptr)
{
    __shared__ int buf[1024];
    __shared__ int carry;
    if (threadIdx.x == 0) carry = 0;
    __syncthreads();
    for (int base = 0; base < NN; base += 1024) {
        int i = base + threadIdx.x;
        int v = (i < NN) ? cnt[i] : 0;
        buf[threadIdx.x] = v;
        __syncthreads();
        for (int off = 1; off < 1024; off <<= 1) {
            int t = (threadIdx.x >= (unsigned)off) ? buf[threadIdx.x - off] : 0;
            __syncthreads();
            buf[threadIdx.x] += t;
            __syncthreads();
        }
        if (i < NN) rowptr[i] = carry + buf[threadIdx.x] - v;
        __syncthreads();
        if (threadIdx.x == 0) carry += buf[1023];
        __syncthreads();
    }
    if (threadIdx.x == 0) rowptr[NN] = carry;
}

// ---------------- CSR fill ---------------------------------------------------
__global__ void k_fill(const int* __restrict__ ei, const float* __restrict__ ea,
                       const int* __restrict__ rowptr, int* __restrict__ cursor,
                       const float* __restrict__ disp, const float* __restrict__ disn,
                       int* __restrict__ colsrc, float* __restrict__ normp, float* __restrict__ normn)
{
    int e = blockIdx.x * blockDim.x + threadIdx.x;
    if (e >= NE) return;
    int s = ei[e], d = ei[NE + e];
    int slot = atomicAdd(&cursor[d], 1);
    int idx = rowptr[d] + slot;
    colsrc[idx] = s;
    normp[idx] = disp[s] * (ea[e * 2 + 0] + 1.f) * disp[d];
    normn[idx] = disn[s] * (ea[e * 2 + 1] + 1.f) * disn[d];
}

// ---------------- W transpose+cast: Wt0[n][k] = (f16)W[k][n] ----------------
__global__ __launch_bounds__(256) void k_wsplit(const float* __restrict__ W, f16* __restrict__ Wt)
{
    __shared__ float t[32][33];
    int bx = blockIdx.x * 32;
    int by = blockIdx.y * 32;
    int tx = threadIdx.x & 31, ty = threadIdx.x >> 5;
#pragma unroll
    for (int j = 0; j < 4; ++j)
        t[ty + j * 8][tx] = W[(size_t)(bx + ty + j * 8) * 640 + by + tx];
    __syncthreads();
#pragma unroll
    for (int j = 0; j < 4; ++j)
        Wt[(size_t)(by + ty + j * 8) * 640 + bx + tx] = (f16)t[tx][ty + j * 8];
}

// ---------------- permute rows+cols to f' order -----------------------------
__global__ __launch_bounds__(640) void k_perm(const f16* __restrict__ Wt0, f16* __restrict__ Wt)
{
    __shared__ f16 row[FF];
    int np = blockIdx.x;
    int n = (np & 63) * 10 + (np >> 6);
    int tid = threadIdx.x;
    row[tid] = Wt0[(size_t)n * FF + tid];
    __syncthreads();
    int k = (tid & 63) * 10 + (tid >> 6);
    Wt[(size_t)np * FF + tid] = row[k];
}

// ---------------- gW transpose: gWt[d][c] = (f16)gW[c][d] -------------------
__global__ void k_gwt(const float* __restrict__ gW, f16* __restrict__ gWt)
{
    int tid = blockIdx.x * 256 + threadIdx.x;
    if (tid >= 128 * 64) return;
    int c = tid >> 6, d = tid & 63;
    gWt[d * 128 + c] = (f16)gW[tid];
}

// ---------------- f16 MFMA GEMM: C[M,640] = A[M,640] @ Bt^T (f16 out) -------
__global__ __launch_bounds__(256) void k_gemm16(const f16* __restrict__ A,
                                                const f16* __restrict__ Bt,
                                                f16* __restrict__ C, int M)
{
    __shared__ f16 As[128][40];
    __shared__ f16 Bs[64][40];
    int tid = threadIdx.x;
    int row0 = blockIdx.x * 128;
    int col0 = blockIdx.y * 64;
    int w = tid >> 6, l = tid & 63;
    int wr = (w >> 1) * 64;
    int wc = (w & 1) * 32;
    int lrow = l & 15;
    int lk = (l >> 4) * 8;
    int srow = tid >> 2;
    int sseg = (tid & 3) * 8;

    f32x4 acc[4][2];
#pragma unroll
    for (int m = 0; m < 4; ++m)
#pragma unroll
        for (int n = 0; n < 2; ++n)
            acc[m][n] = (f32x4){0.f, 0.f, 0.f, 0.f};

    for (int k0 = 0; k0 < FF; k0 += 32) {
        f16x8 a0 = {}, a1 = {};
        int r0 = row0 + srow, r1 = row0 + srow + 64;
        if (r0 < M) a0 = *(const f16x8*)&A[(size_t)r0 * FF + k0 + sseg];
        if (r1 < M) a1 = *(const f16x8*)&A[(size_t)r1 * FF + k0 + sseg];
        f16x8 b0 = *(const f16x8*)&Bt[(size_t)(col0 + srow) * FF + k0 + sseg];
        __syncthreads();
        *(f16x8*)&As[srow][sseg]      = a0;
        *(f16x8*)&As[srow + 64][sseg] = a1;
        *(f16x8*)&Bs[srow][sseg]      = b0;
        __syncthreads();
        f16x8 af[4], bf[2];
#pragma unroll
        for (int m = 0; m < 4; ++m)
            af[m] = *(const f16x8*)&As[wr + m * 16 + lrow][lk];
#pragma unroll
        for (int n = 0; n < 2; ++n)
            bf[n] = *(const f16x8*)&Bs[wc + n * 16 + lrow][lk];
#pragma unroll
        for (int m = 0; m < 4; ++m)
#pragma unroll
            for (int n = 0; n < 2; ++n)
                acc[m][n] = __builtin_amdgcn_mfma_f32_16x16x32_f16(af[m], bf[n], acc[m][n], 0, 0, 0);
    }
    int orow = (l >> 4) * 4;
#pragma unroll
    for (int m = 0; m < 4; ++m) {
#pragma unroll
        for (int r = 0; r < 4; ++r) {
            int rr = row0 + wr + m * 16 + orow + r;
            if (rr < M) {
#pragma unroll
                for (int n = 0; n < 2; ++n)
                    C[(size_t)rr * FF + col0 + wc + n * 16 + lrow] = (f16)acc[m][n][r];
            }
        }
    }
}

// ---------------- GCN aggregate (LDS-preloaded indices, f16x2 lanes) --------
// 320 threads = 5 waves; thread f2 handles columns 2*f2, 2*f2+1
__global__ __launch_bounds__(320) void k_agg(const f16* __restrict__ hsrc,
                      const int* __restrict__ rowptr, const int* __restrict__ colsrc,
                      const float* __restrict__ enorm, const float* __restrict__ dis,
                      const float* __restrict__ bias, f16* __restrict__ hout)
{
    __shared__ int   s_idx[128];
    __shared__ float s_w[128];
    int d = blockIdx.x;
    int f2 = threadIdx.x;
    int c0 = f2 * 2, c1 = c0 + 1;
    float selfw = dis[d] * dis[d];
    f16x2 self = *(const f16x2*)&hsrc[(size_t)d * FF + c0];
    float v0 = selfw * (float)self[0];
    float v1 = selfw * (float)self[1];
    int beg = rowptr[d], end = rowptr[d + 1];
    for (int base = beg; base < end; base += 128) {
        int cnt = (end - base < 128) ? (end - base) : 128;
        __syncthreads();
        if (threadIdx.x < (unsigned)cnt) {
            s_idx[threadIdx.x] = colsrc[base + threadIdx.x];
            s_w[threadIdx.x]   = enorm[base + threadIdx.x];
        }
        __syncthreads();
        for (int i = 0; i < cnt; ++i) {
            f16x2 p = *(const f16x2*)&hsrc[(size_t)s_idx[i] * FF + c0];
            float w = s_w[i];
            v0 += w * (float)p[0];
            v1 += w * (float)p[1];
        }
    }
    v0 += bias[(c0 & 63) * 10 + (c0 >> 6)];
    v1 += bias[(c1 & 63) * 10 + (c1 >> 6)];
    f16x2 o;
    o[0] = (f16)fmaxf(v0, 0.f);
    o[1] = (f16)fmaxf(v1, 0.f);
    *(f16x2*)&hout[(size_t)d * FF + c0] = o;
}

// ---------------- GReTo mix as MFMA GEMM (f16 out) --------------------------
__global__ __launch_bounds__(256) void k_greto2(const f16* __restrict__ h1,
                        const f16* __restrict__ h2, const f16* __restrict__ h3,
                        const f16* __restrict__ hneg, const float* __restrict__ psi,
                        const f16* __restrict__ gWt, const float* __restrict__ gb,
                        f16* __restrict__ out)
{
    __shared__ f16 As[128][132];
    __shared__ f16 Bs[64][132];
    int tid = threadIdx.x;
    int row0 = blockIdx.x * 128;

    for (int cb = tid; cb < 1024; cb += 256) {
        int d = cb >> 4, seg = (cb & 15) * 8;
        *(f16x8*)&Bs[d][seg] = *(const f16x8*)&gWt[d * 128 + seg];
    }
    int lr = tid >> 1, side = tid & 1;
    int r = row0 + lr;
    if (r < NR) {
        int n = r / 10, t = r - (r / 10) * 10;
        size_t base = (size_t)n * FF + t * 64;
        if (side == 0) {
            float p0 = psi[n * 3], p1 = psi[n * 3 + 1], p2 = psi[n * 3 + 2];
#pragma unroll
            for (int i = 0; i < 8; ++i) {
                f16x8 a = *(const f16x8*)&h1[base + i * 8];
                f16x8 b = *(const f16x8*)&h2[base + i * 8];
                f16x8 c = *(const f16x8*)&h3[base + i * 8];
                f16x8 o;
#pragma unroll
                for (int j = 0; j < 8; ++j)
                    o[j] = (f16)(p0 * (float)a[j] + p1 * (float)b[j] + p2 * (float)c[j]);
                *(f16x8*)&As[lr][i * 8] = o;
            }
        } else {
#pragma unroll
            for (int i = 0; i < 8; ++i)
                *(f16x8*)&As[lr][64 + i * 8] = *(const f16x8*)&hneg[base + i * 8];
        }
    } else {
        f16x8 z = {};
#pragma unroll
        for (int i = 0; i < 8; ++i)
            *(f16x8*)&As[lr][side * 64 + i * 8] = z;
    }
    __syncthreads();

    int w = tid >> 6, l = tid & 63;
    int wr = w * 32;
    int lrow = l & 15;
    int lk = (l >> 4) * 8;
    f32x4 acc[2][4];
#pragma unroll
    for (int m = 0; m < 2; ++m)
#pragma unroll
        for (int n = 0; n < 4; ++n)
            acc[m][n] = (f32x4){0.f, 0.f, 0.f, 0.f};
#pragma unroll
    for (int ks = 0; ks < 4; ++ks) {
        f16x8 af[2], bf[4];
#pragma unroll
        for (int m = 0; m < 2; ++m)
            af[m] = *(const f16x8*)&As[wr + m * 16 + lrow][ks * 32 + lk];
#pragma unroll
        for (int n = 0; n < 4; ++n)
            bf[n] = *(const f16x8*)&Bs[n * 16 + lrow][ks * 32 + lk];
#pragma unroll
        for (int m = 0; m < 2; ++m)
#pragma unroll
            for (int n = 0; n < 4; ++n)
                acc[m][n] = __builtin_amdgcn_mfma_f32_16x16x32_f16(af[m], bf[n], acc[m][n], 0, 0, 0);
    }
    int orow = (l >> 4) * 4;
#pragma unroll
    for (int m = 0; m < 2; ++m) {
#pragma unroll
        for (int rr = 0; rr < 4; ++rr) {
            int ro = row0 + wr + m * 16 + orow + rr;
            if (ro < NR) {
#pragma unroll
                for (int n = 0; n < 4; ++n) {
                    int col = n * 16 + lrow;
                    out[(size_t)ro * 64 + col] = (f16)fmaxf(acc[m][n][rr] + gb[col], 0.f);
                }
            }
        }
    }
}

extern "C" void kernel_launch(void* const* d_in, const int* in_sizes, int n_in,
                              void* d_out, int out_size, void* d_ws, size_t ws_size,
                              hipStream_t stream)
{
    const float* x     = (const float*)d_in[0];
    const int*   ei    = (const int*)  d_in[1];
    const float* ea    = (const float*)d_in[2];
    const float* ndt   = (const float*)d_in[3];
    const float* tc1w1 = (const float*)d_in[4];
    const float* tc1b1 = (const float*)d_in[5];
    const float* tc1w2 = (const float*)d_in[6];
    const float* tc1b2 = (const float*)d_in[7];
    const float* Wpos  = (const float*)d_in[8];
    const float* bpos  = (const float*)d_in[9];
    const float* Wneg  = (const float*)d_in[10];
    const float* bneg  = (const float*)d_in[11];
    const float* greW  = (const float*)d_in[12];
    const float* greb  = (const float*)d_in[13];
    const float* psiW1 = (const float*)d_in[14];
    const float* psib1 = (const float*)d_in[15];
    const float* psiW2 = (const float*)d_in[16];
    const float* psib2 = (const float*)d_in[17];
    const float* tc2w1 = (const float*)d_in[18];
    const float* tc2b1 = (const float*)d_in[19];
    const float* tc2w2 = (const float*)d_in[20];
    const float* tc2b2 = (const float*)d_in[21];
    float* out = (float*)d_out;

    char* p = (char*)d_ws;
    f16*   xT    = (f16*)p;   p += (size_t)NN * CCH * TIN * 2;
    f16*   out0h = (f16*)p;   p += (size_t)NN * FF * 2;
    f16*   h1    = (f16*)p;   p += (size_t)NN * FF * 2;
    f16*   h2    = (f16*)p;   p += (size_t)NN * FF * 2;
    f16*   h3    = (f16*)p;   p += (size_t)NN * FF * 2;
    f16*   hneg  = (f16*)p;   p += (size_t)NN * FF * 2;
    f16*   Cb16  = (f16*)p;   p += (size_t)NN * FF * 2;
    f16*   Gbuf  = (f16*)p;   p += (size_t)NN * FF * 2;
    f16*   Wtp   = (f16*)p;   p += (size_t)FF * FF * 2;
    f16*   Wtn   = (f16*)p;   p += (size_t)FF * FF * 2;
    f16*   Wtmp  = (f16*)p;   p += (size_t)FF * FF * 2;
    f16*   gWt   = (f16*)p;   p += (size_t)128 * 64 * 2;
    f16*   Bw1   = (f16*)p;   p += (size_t)128 * 192 * 2;
    f16*   Bw2   = (f16*)p;   p += (size_t)128 * 192 * 2;
    float* psib  = (float*)p; p += (size_t)NN * 3 * 4;
    float* degp  = (float*)p; p += (size_t)NN * 4;
    float* degn  = (float*)p; p += (size_t)NN * 4;
    float* disp  = (float*)p; p += (size_t)NN * 4;
    float* disn  = (float*)p; p += (size_t)NN * 4;
    float* normp = (float*)p; p += (size_t)NE * 4;
    float* normn = (float*)p; p += (size_t)NE * 4;
    int* cnt     = (int*)p;   p += (size_t)NN * 4;
    int* rowptr  = (int*)p;   p += (size_t)(NN + 1) * 4;
    int* cursor  = (int*)p;   p += (size_t)NN * 4;
    int* colsrc  = (int*)p;   p += (size_t)NE * 4;

    (void)hipMemsetAsync(cnt, 0, NN * 4, stream);
    (void)hipMemsetAsync(cursor, 0, NN * 4, stream);
    (void)hipMemsetAsync(degp, 0, NN * 4, stream);
    (void)hipMemsetAsync(degn, 0, NN * 4, stream);

    k_xT<<<2500, 256, 0, stream>>>(x, xT);
    k_wconv<<<(128 * 192 + 255) / 256, 256, 0, stream>>>(tc1w1, tc1w2, Bw1);
    k_wconv<<<(128 * 192 + 255) / 256, 256, 0, stream>>>(tc2w1, tc2w2, Bw2);
    k_tcn1g<<<(NR + 127) / 128, 256, 0, stream>>>(xT, Bw1, tc1b1, tc1b2, out0h);
    k_psi<<<(NN + 255) / 256, 256, 0, stream>>>(ndt, psiW1, psib1, psiW2, psib2, psib);
    k_deg<<<(NE + 255) / 256, 256, 0, stream>>>(ei, ea, cnt, degp, degn);
    k_dis<<<(NN + 255) / 256, 256, 0, stream>>>(degp, degn, disp, disn);
    k_scan<<<1, 1024, 0, stream>>>(cnt, rowptr);
    k_fill<<<(NE + 255) / 256, 256, 0, stream>>>(ei, ea, rowptr, cursor, disp, disn,
                                                 colsrc, normp, normn);
    dim3 wgrid(20, 20);
    k_wsplit<<<wgrid, 256, 0, stream>>>(Wpos, Wtmp);
    k_perm<<<FF, 640, 0, stream>>>(Wtmp, Wtp);
    k_wsplit<<<wgrid, 256, 0, stream>>>(Wneg, Wtmp);
    k_perm<<<FF, 640, 0, stream>>>(Wtmp, Wtn);
    k_gwt<<<(128 * 64 + 255) / 256, 256, 0, stream>>>(greW, gWt);

    dim3 ggrid((NN + 127) / 128, FF / 64);
    // positive hops
    k_gemm16<<<ggrid, 256, 0, stream>>>(out0h, Wtp, Cb16, NN);
    k_agg<<<NN, 320, 0, stream>>>(Cb16, rowptr, colsrc, normp, disp, bpos, h1);
    k_gemm16<<<ggrid, 256, 0, stream>>>(h1, Wtp, Cb16, NN);
    k_agg<<<NN, 320, 0, stream>>>(Cb16, rowptr, colsrc, normp, disp, bpos, h2);
    k_gemm16<<<ggrid, 256, 0, stream>>>(h2, Wtp, Cb16, NN);
    k_agg<<<NN, 320, 0, stream>>>(Cb16, rowptr, colsrc, normp, disp, bpos, h3);
    // negative branch
    k_gemm16<<<ggrid, 256, 0, stream>>>(out0h, Wtn, Cb16, NN);
    k_agg<<<NN, 320, 0, stream>>>(Cb16, rowptr, colsrc, normn, disn, bneg, hneg);
    // GReTo channel mix (MFMA) + psi accumulation + relu -> f16
    k_greto2<<<(NR + 127) / 128, 256, 0, stream>>>(h1, h2, h3, hneg, psib, gWt, greb, Gbuf);
    // final gated TCN as direct GEMM
    k_tcn2g<<<(NR2 + 127) / 128, 256, 0, stream>>>(Gbuf, Bw2, tc2b1, tc2b2, out);
}

// Round 14
// 432.944 us; speedup vs baseline: 3.4976x; 1.0725x over previous
//
#include <hip/hip_runtime.h>
#include <math.h>

#define NN   10000   // nodes
#define NE   160000  // edges
#define CCH  64      // in/out channels
#define TIN  12      // input time steps
#define HCH  64      // hidden channels
#define TSP  10      // T - 2
#define FF   640     // H * TSP
#define TOUT 8       // TSP - 2
#define NR   (NN * TSP)    // 100000 rows for tcn1 / GCN / greto
#define NR2  (NN * TOUT)   // 80000 rows for tcn2

// GCN feature ordering: f' = t*64 + h (channel-contiguous rows)

typedef _Float16 f16;
typedef _Float16 f16x2 __attribute__((ext_vector_type(2)));
typedef _Float16 f16x8 __attribute__((ext_vector_type(8)));
typedef float f32x4 __attribute__((ext_vector_type(4)));

// async global->LDS, 16B per lane, wave-uniform LDS base + lane*16
#define GLD_LDS(gsrc, ldst) __builtin_amdgcn_global_load_lds( \
    (const __attribute__((address_space(1))) void*)(gsrc),    \
    (__attribute__((address_space(3))) void*)(ldst), 16, 0, 0)

// ---------------- x transpose: xT[n][t][c] = (f16)x[n][c][t] ----------------
__global__ __launch_bounds__(256) void k_xT(const float* __restrict__ x, f16* __restrict__ xT)
{
    __shared__ float xs[4][CCH * TIN];
    int node0 = blockIdx.x * 4;
    for (int i = threadIdx.x; i < 4 * CCH * TIN; i += 256) {
        int nn = i / (CCH * TIN), off = i % (CCH * TIN);
        int g = node0 + nn;
        xs[nn][off] = (g < NN) ? x[(size_t)g * CCH * TIN + off] : 0.f;
    }
    __syncthreads();
    for (int i = threadIdx.x; i < 4 * CCH * TIN; i += 256) {
        int nn = i / (CCH * TIN), off = i % (CCH * TIN);
        int t = off >> 6, c = off & 63;
        int g = node0 + nn;
        if (g < NN) xT[(size_t)g * (CCH * TIN) + off] = (f16)xs[nn][c * TIN + t];
    }
}

// ---------------- conv weights -> Bw[o][k*64+ci] f16 ------------------------
__global__ void k_wconv(const float* __restrict__ w1, const float* __restrict__ w2,
                        f16* __restrict__ dst)
{
    int tid = blockIdx.x * 256 + threadIdx.x;
    if (tid >= 128 * 192) return;
    int o = tid / 192, j = tid % 192;
    int k = j >> 6, ci = j & 63;
    const float* src = (o < 64) ? w1 : w2;
    dst[tid] = (f16)src[((o & 63) * 64 + ci) * 3 + k];
}

// ---------------- TCN1 as direct GEMM, B staged in LDS ----------------------
__global__ __launch_bounds__(256) void k_tcn1g(const f16* __restrict__ A,   // xT [NN][768]
                                               const f16* __restrict__ Bw,
                                               const float* __restrict__ b1,
                                               const float* __restrict__ b2,
                                               f16* __restrict__ out)       // [NR][64] = f' order
{
    __shared__ f16 Bs[128][200];   // padded: row stride 100 dwords -> 2-way alias only
    int tid = threadIdx.x;
#pragma unroll
    for (int i = 0; i < 12; ++i) {
        int c = tid + i * 256;             // 3072 f16x8 chunks
        int row = c / 24, seg = (c % 24) * 8;
        *(f16x8*)&Bs[row][seg] = *(const f16x8*)&Bw[row * 192 + seg];
    }
    __syncthreads();

    int w = tid >> 6, l = tid & 63;
    int row0 = blockIdx.x * 128 + w * 32;
    int lrow = l & 15, lk = (l >> 4) * 8;

    size_t abase[2];
#pragma unroll
    for (int m = 0; m < 2; ++m) {
        int rr = row0 + m * 16 + lrow;
        int rc = (rr < NR) ? rr : NR - 1;
        int n = rc / 10, t = rc - n * 10;
        abase[m] = (size_t)n * 768 + t * 64 + lk;
    }
    f32x4 acc[2][8];
#pragma unroll
    for (int m = 0; m < 2; ++m)
#pragma unroll
        for (int n = 0; n < 8; ++n)
            acc[m][n] = (f32x4){0.f, 0.f, 0.f, 0.f};

#pragma unroll
    for (int ks = 0; ks < 6; ++ks) {
        f16x8 af[2], bf[8];
#pragma unroll
        for (int m = 0; m < 2; ++m)
            af[m] = *(const f16x8*)&A[abase[m] + ks * 32];
#pragma unroll
        for (int n = 0; n < 8; ++n)
            bf[n] = *(const f16x8*)&Bs[n * 16 + lrow][ks * 32 + lk];
#pragma unroll
        for (int m = 0; m < 2; ++m)
#pragma unroll
            for (int n = 0; n < 8; ++n)
                acc[m][n] = __builtin_amdgcn_mfma_f32_16x16x32_f16(af[m], bf[n], acc[m][n], 0, 0, 0);
    }
    int og = (l >> 4) * 4;
#pragma unroll
    for (int m = 0; m < 2; ++m) {
#pragma unroll
        for (int n = 0; n < 4; ++n) {
            int h = n * 16 + lrow;
            float bb1 = b1[h], bb2 = b2[h];
#pragma unroll
            for (int rr = 0; rr < 4; ++rr) {
                int R = row0 + m * 16 + og + rr;
                if (R < NR) {
                    float g1 = acc[m][n][rr] + bb1;
                    float g2 = acc[m][n + 4][rr] + bb2;
                    float e = __expf(2.f * g1);
                    float th = 1.f - 2.f / (e + 1.f);
                    float sg = 1.f / (1.f + __expf(-g2));
                    out[(size_t)R * 64 + h] = (f16)(th * sg);
                }
            }
        }
    }
}

// TCN2: A = Gbuf [NN][640] f16, rows r=n*8+t, slice at n*640+t*64; f32 out [N,64,8]
__global__ __launch_bounds__(256) void k_tcn2g(const f16* __restrict__ A,
                                               const f16* __restrict__ Bw,
                                               const float* __restrict__ b1,
                                               const float* __restrict__ b2,
                                               float* __restrict__ out)
{
    __shared__ f16 Bs[128][200];
    int tid = threadIdx.x;
#pragma unroll
    for (int i = 0; i < 12; ++i) {
        int c = tid + i * 256;
        int row = c / 24, seg = (c % 24) * 8;
        *(f16x8*)&Bs[row][seg] = *(const f16x8*)&Bw[row * 192 + seg];
    }
    __syncthreads();

    int w = tid >> 6, l = tid & 63;
    int row0 = blockIdx.x * 128 + w * 32;
    int lrow = l & 15, lk = (l >> 4) * 8;

    size_t abase[2];
#pragma unroll
    for (int m = 0; m < 2; ++m) {
        int rr = row0 + m * 16 + lrow;
        int rc = (rr < NR2) ? rr : NR2 - 1;
        int n = rc >> 3, t = rc & 7;
        abase[m] = (size_t)n * FF + t * 64 + lk;
    }
    f32x4 acc[2][8];
#pragma unroll
    for (int m = 0; m < 2; ++m)
#pragma unroll
        for (int n = 0; n < 8; ++n)
            acc[m][n] = (f32x4){0.f, 0.f, 0.f, 0.f};

#pragma unroll
    for (int ks = 0; ks < 6; ++ks) {
        f16x8 af[2], bf[8];
#pragma unroll
        for (int m = 0; m < 2; ++m)
            af[m] = *(const f16x8*)&A[abase[m] + ks * 32];
#pragma unroll
        for (int n = 0; n < 8; ++n)
            bf[n] = *(const f16x8*)&Bs[n * 16 + lrow][ks * 32 + lk];
#pragma unroll
        for (int m = 0; m < 2; ++m)
#pragma unroll
            for (int n = 0; n < 8; ++n)
                acc[m][n] = __builtin_amdgcn_mfma_f32_16x16x32_f16(af[m], bf[n], acc[m][n], 0, 0, 0);
    }
    int og = (l >> 4) * 4;
#pragma unroll
    for (int m = 0; m < 2; ++m) {
#pragma unroll
        for (int n = 0; n < 4; ++n) {
            int c = n * 16 + lrow;
            float bb1 = b1[c], bb2 = b2[c];
#pragma unroll
            for (int rr = 0; rr < 4; ++rr) {
                int R = row0 + m * 16 + og + rr;
                if (R < NR2) {
                    float g1 = acc[m][n][rr] + bb1;
                    float g2 = acc[m][n + 4][rr] + bb2;
                    float e = __expf(2.f * g1);
                    float th = 1.f - 2.f / (e + 1.f);
                    float sg = 1.f / (1.f + __expf(-g2));
                    int n2 = R >> 3, t2 = R & 7;
                    out[(size_t)n2 * (CCH * TOUT) + c * TOUT + t2] = th * sg;
                }
            }
        }
    }
}

// ---------------- psi MLP ---------------------------------------------------
__global__ void k_psi(const float* __restrict__ ND, const float* __restrict__ W1,
                      const float* __restrict__ b1, const float* __restrict__ W2,
                      const float* __restrict__ b2, float* __restrict__ psi)
{
    int n = blockIdx.x * blockDim.x + threadIdx.x;
    if (n >= NN) return;
    float d0 = ND[n * 3], d1 = ND[n * 3 + 1], d2 = ND[n * 3 + 2];
    float o0 = b2[0], o1 = b2[1], o2 = b2[2];
    for (int j = 0; j < 64; ++j) {
        float hv = d0 * W1[j] + d1 * W1[64 + j] + d2 * W1[128 + j] + b1[j];
        hv = fmaxf(hv, 0.f);
        o0 += hv * W2[j * 3 + 0];
        o1 += hv * W2[j * 3 + 1];
        o2 += hv * W2[j * 3 + 2];
    }
    psi[n * 3 + 0] = o0; psi[n * 3 + 1] = o1; psi[n * 3 + 2] = o2;
}

// ---------------- degree / counts -------------------------------------------
__global__ void k_deg(const int* __restrict__ ei, const float* __restrict__ ea,
                      int* __restrict__ cnt, float* __restrict__ degp, float* __restrict__ degn)
{
    int e = blockIdx.x * blockDim.x + threadIdx.x;
    if (e >= NE) return;
    int d = ei[NE + e];
    atomicAdd(&cnt[d], 1);
    atomicAdd(&degp[d], ea[e * 2 + 0] + 1.f);
    atomicAdd(&degn[d], ea[e * 2 + 1] + 1.f);
}

__global__ void k_dis(const float* __restrict__ degp, const float* __restrict__ degn,
                      float* __restrict__ disp, float* __restrict__ disn)
{
    int n = blockIdx.x * blockDim.x + threadIdx.x;
    if (n >= NN) return;
    disp[n] = 1.f / sqrtf(degp[n] + 1.f);
    disn[n] = 1.f / sqrtf(degn[n] + 1.f);
}

// ---------------- exclusive scan --------------------------------------------
__global__ __launch_bounds__(1024) void k_scan(const int* __restrict__ cnt, int* __restrict__ rowptr)
{
    __shared__ int buf[1024];
    __shared__ int carry;
    if (threadIdx.x == 0) carry = 0;
    __syncthreads();
    for (int base = 0; base < NN; base += 1024) {
        int i = base + threadIdx.x;
        int v = (i < NN) ? cnt[i] : 0;
        buf[threadIdx.x] = v;
        __syncthreads();
        for (int off = 1; off < 1024; off <<= 1) {
            int t = (threadIdx.x >= (unsigned)off) ? buf[threadIdx.x - off] : 0;
            __syncthreads();
            buf[threadIdx.x] += t;
            __syncthreads();
        }
        if (i < NN) rowptr[i] = carry + buf[threadIdx.x] - v;
        __syncthreads();
        if (threadIdx.x == 0) carry += buf[1023];
        __syncthreads();
    }
    if (threadIdx.x == 0) rowptr[NN] = carry;
}

// ---------------- CSR fill ---------------------------------------------------
__global__ void k_fill(const int* __restrict__ ei, const float* __restrict__ ea,
                       const int* __restrict__ rowptr, int* __restrict__ cursor,
                       const float* __restrict__ disp, const float* __restrict__ disn,
                       int* __restrict__ colsrc, float* __restrict__ normp, float* __restrict__ normn)
{
    int e = blockIdx.x * blockDim.x + threadIdx.x;
    if (e >= NE) return;
    int s = ei[e], d = ei[NE + e];
    int slot = atomicAdd(&cursor[d], 1);
    int idx = rowptr[d] + slot;
    colsrc[idx] = s;
    normp[idx] = disp[s] * (ea[e * 2 + 0] + 1.f) * disp[d];
    normn[idx] = disn[s] * (ea[e * 2 + 1] + 1.f) * disn[d];
}

// ---------------- W transpose+cast: Wt0[n][k] = (f16)W[k][n] ----------------
__global__ __launch_bounds__(256) void k_wsplit(const float* __restrict__ W, f16* __restrict__ Wt)
{
    __shared__ float t[32][33];
    int bx = blockIdx.x * 32;
    int by = blockIdx.y * 32;
    int tx = threadIdx.x & 31, ty = threadIdx.x >> 5;
#pragma unroll
    for (int j = 0; j < 4; ++j)
        t[ty + j * 8][tx] = W[(size_t)(bx + ty + j * 8) * 640 + by + tx];
    __syncthreads();
#pragma unroll
    for (int j = 0; j < 4; ++j)
        Wt[(size_t)(by + ty + j * 8) * 640 + bx + tx] = (f16)t[tx][ty + j * 8];
}

// ---------------- permute rows+cols to f' order -----------------------------
__global__ __launch_bounds__(640) void k_perm(const f16* __restrict__ Wt0, f16* __restrict__ Wt)
{
    __shared__ f16 row[FF];
    int np = blockIdx.x;
    int n = (np & 63) * 10 + (np >> 6);
    int tid = threadIdx.x;
    row[tid] = Wt0[(size_t)n * FF + tid];
    __syncthreads();
    int k = (tid & 63) * 10 + (tid >> 6);
    Wt[(size_t)np * FF + tid] = row[k];
}

// ---------------- gW transpose: gWt[d][c] = (f16)gW[c][d] -------------------
__global__ void k_gwt(const float* __restrict__ gW, f16* __restrict__ gWt)
{
    int tid = blockIdx.x * 256 + threadIdx.x;
    if (tid >= 128 * 64) return;
    int c = tid >> 6, d = tid & 63;
    gWt[d * 128 + c] = (f16)gW[tid];
}

// ---------------- f16 MFMA GEMM with global_load_lds staging ----------------
// C[M,640] = A[M,640] @ Bt^T (f16 out); tile 128x64, BK=32, 4 waves
__global__ __launch_bounds__(256) void k_gemm16(const f16* __restrict__ A,
                                                const f16* __restrict__ Bt,
                                                f16* __restrict__ C, int M)
{
    __shared__ f16 As[128 * 32];   // linear [row][32]
    __shared__ f16 Bs[64 * 32];
    int tid = threadIdx.x;
    int row0 = blockIdx.x * 128;
    int col0 = blockIdx.y * 64;
    int w = tid >> 6, l = tid & 63;
    int wr = (w >> 1) * 64;
    int wc = (w & 1) * 32;
    int lrow = l & 15;
    int lk = (l >> 4) * 8;

    // staging geometry: lane l covers row (l>>2), col (l&3)*8 within a 16-row slab
    int arow = w * 32 + (l >> 2);          // A rows slab for this wave (+16 for 2nd instr)
    int brow = w * 16 + (l >> 2);          // B rows slab
    int seg  = (l & 3) * 8;

    f32x4 acc[4][2];
#pragma unroll
    for (int m = 0; m < 4; ++m)
#pragma unroll
        for (int n = 0; n < 2; ++n)
            acc[m][n] = (f32x4){0.f, 0.f, 0.f, 0.f};

    for (int k0 = 0; k0 < FF; k0 += 32) {
        __syncthreads();   // prior iteration's LDS reads done
        GLD_LDS(&A[(size_t)(row0 + arow) * FF + k0 + seg],       &As[w * 1024]);
        GLD_LDS(&A[(size_t)(row0 + arow + 16) * FF + k0 + seg],  &As[w * 1024 + 512]);
        GLD_LDS(&Bt[(size_t)(col0 + brow) * FF + k0 + seg],      &Bs[w * 512]);
        __syncthreads();   // drains vmcnt before reads
        f16x8 af[4], bf[2];
#pragma unroll
        for (int m = 0; m < 4; ++m)
            af[m] = *(const f16x8*)&As[(wr + m * 16 + lrow) * 32 + lk];
#pragma unroll
        for (int n = 0; n < 2; ++n)
            bf[n] = *(const f16x8*)&Bs[(wc + n * 16 + lrow) * 32 + lk];
#pragma unroll
        for (int m = 0; m < 4; ++m)
#pragma unroll
            for (int n = 0; n < 2; ++n)
                acc[m][n] = __builtin_amdgcn_mfma_f32_16x16x32_f16(af[m], bf[n], acc[m][n], 0, 0, 0);
    }
    int orow = (l >> 4) * 4;
#pragma unroll
    for (int m = 0; m < 4; ++m) {
#pragma unroll
        for (int r = 0; r < 4; ++r) {
            int rr = row0 + wr + m * 16 + orow + r;
            if (rr < M) {
#pragma unroll
                for (int n = 0; n < 2; ++n)
                    C[(size_t)rr * FF + col0 + wc + n * 16 + lrow] = (f16)acc[m][n][r];
            }
        }
    }
}

// ---------------- GCN aggregate (LDS-preloaded indices, f16x2 lanes) --------
__global__ __launch_bounds__(320) void k_agg(const f16* __restrict__ hsrc,
                      const int* __restrict__ rowptr, const int* __restrict__ colsrc,
                      const float* __restrict__ enorm, const float* __restrict__ dis,
                      const float* __restrict__ bias, f16* __restrict__ hout)
{
    __shared__ int   s_idx[128];
    __shared__ float s_w[128];
    int d = blockIdx.x;
    int f2 = threadIdx.x;
    int c0 = f2 * 2, c1 = c0 + 1;
    float selfw = dis[d] * dis[d];
    f16x2 self = *(const f16x2*)&hsrc[(size_t)d * FF + c0];
    float v0 = selfw * (float)self[0];
    float v1 = selfw * (float)self[1];
    int beg = rowptr[d], end = rowptr[d + 1];
    for (int base = beg; base < end; base += 128) {
        int cnt = (end - base < 128) ? (end - base) : 128;
        __syncthreads();
        if (threadIdx.x < (unsigned)cnt) {
            s_idx[threadIdx.x] = colsrc[base + threadIdx.x];
            s_w[threadIdx.x]   = enorm[base + threadIdx.x];
        }
        __syncthreads();
        for (int i = 0; i < cnt; ++i) {
            f16x2 p = *(const f16x2*)&hsrc[(size_t)s_idx[i] * FF + c0];
            float w = s_w[i];
            v0 += w * (float)p[0];
            v1 += w * (float)p[1];
        }
    }
    v0 += bias[(c0 & 63) * 10 + (c0 >> 6)];
    v1 += bias[(c1 & 63) * 10 + (c1 >> 6)];
    f16x2 o;
    o[0] = (f16)fmaxf(v0, 0.f);
    o[1] = (f16)fmaxf(v1, 0.f);
    *(f16x2*)&hout[(size_t)d * FF + c0] = o;
}

// ---------------- GReTo mix as MFMA GEMM (f16 out) --------------------------
__global__ __launch_bounds__(256) void k_greto2(const f16* __restrict__ h1,
                        const f16* __restrict__ h2, const f16* __restrict__ h3,
                        const f16* __restrict__ hneg, const float* __restrict__ psi,
                        const f16* __restrict__ gWt, const float* __restrict__ gb,
                        f16* __restrict__ out)
{
    __shared__ f16 As[128][132];
    __shared__ f16 Bs[64][132];
    int tid = threadIdx.x;
    int row0 = blockIdx.x * 128;

    for (int cb = tid; cb < 1024; cb += 256) {
        int d = cb >> 4, seg = (cb & 15) * 8;
        *(f16x8*)&Bs[d][seg] = *(const f16x8*)&gWt[d * 128 + seg];
    }
    int lr = tid >> 1, side = tid & 1;
    int r = row0 + lr;
    if (r < NR) {
        int n = r / 10, t = r - (r / 10) * 10;
        size_t base = (size_t)n * FF + t * 64;
        if (side == 0) {
            float p0 = psi[n * 3], p1 = psi[n * 3 + 1], p2 = psi[n * 3 + 2];
#pragma unroll
            for (int i = 0; i < 8; ++i) {
                f16x8 a = *(const f16x8*)&h1[base + i * 8];
                f16x8 b = *(const f16x8*)&h2[base + i * 8];
                f16x8 c = *(const f16x8*)&h3[base + i * 8];
                f16x8 o;
#pragma unroll
                for (int j = 0; j < 8; ++j)
                    o[j] = (f16)(p0 * (float)a[j] + p1 * (float)b[j] + p2 * (float)c[j]);
                *(f16x8*)&As[lr][i * 8] = o;
            }
        } else {
#pragma unroll
            for (int i = 0; i < 8; ++i)
                *(f16x8*)&As[lr][64 + i * 8] = *(const f16x8*)&hneg[base + i * 8];
        }
    } else {
        f16x8 z = {};
#pragma unroll
        for (int i = 0; i < 8; ++i)
            *(f16x8*)&As[lr][side * 64 + i * 8] = z;
    }
    __syncthreads();

    int w = tid >> 6, l = tid & 63;
    int wr = w * 32;
    int lrow = l & 15;
    int lk = (l >> 4) * 8;
    f32x4 acc[2][4];
#pragma unroll
    for (int m = 0; m < 2; ++m)
#pragma unroll
        for (int n = 0; n < 4; ++n)
            acc[m][n] = (f32x4){0.f, 0.f, 0.f, 0.f};
#pragma unroll
    for (int ks = 0; ks < 4; ++ks) {
        f16x8 af[2], bf[4];
#pragma unroll
        for (int m = 0; m < 2; ++m)
            af[m] = *(const f16x8*)&As[wr + m * 16 + lrow][ks * 32 + lk];
#pragma unroll
        for (int n = 0; n < 4; ++n)
            bf[n] = *(const f16x8*)&Bs[n * 16 + lrow][ks * 32 + lk];
#pragma unroll
        for (int m = 0; m < 2; ++m)
#pragma unroll
            for (int n = 0; n < 4; ++n)
                acc[m][n] = __builtin_amdgcn_mfma_f32_16x16x32_f16(af[m], bf[n], acc[m][n], 0, 0, 0);
    }
    int orow = (l >> 4) * 4;
#pragma unroll
    for (int m = 0; m < 2; ++m) {
#pragma unroll
        for (int rr = 0; rr < 4; ++rr) {
            int ro = row0 + wr + m * 16 + orow + rr;
            if (ro < NR) {
#pragma unroll
                for (int n = 0; n < 4; ++n) {
                    int col = n * 16 + lrow;
                    out[(size_t)ro * 64 + col] = (f16)fmaxf(acc[m][n][rr] + gb[col], 0.f);
                }
            }
        }
    }
}

extern "C" void kernel_launch(void* const* d_in, const int* in_sizes, int n_in,
                              void* d_out, int out_size, void* d_ws, size_t ws_size,
                              hipStream_t stream)
{
    const float* x     = (const float*)d_in[0];
    const int*   ei    = (const int*)  d_in[1];
    const float* ea    = (const float*)d_in[2];
    const float* ndt   = (const float*)d_in[3];
    const float* tc1w1 = (const float*)d_in[4];
    const float* tc1b1 = (const float*)d_in[5];
    const float* tc1w2 = (const float*)d_in[6];
    const float* tc1b2 = (const float*)d_in[7];
    const float* Wpos  = (const float*)d_in[8];
    const float* bpos  = (const float*)d_in[9];
    const float* Wneg  = (const float*)d_in[10];
    const float* bneg  = (const float*)d_in[11];
    const float* greW  = (const float*)d_in[12];
    const float* greb  = (const float*)d_in[13];
    const float* psiW1 = (const float*)d_in[14];
    const float* psib1 = (const float*)d_in[15];
    const float* psiW2 = (const float*)d_in[16];
    const float* psib2 = (const float*)d_in[17];
    const float* tc2w1 = (const float*)d_in[18];
    const float* tc2b1 = (const float*)d_in[19];
    const float* tc2w2 = (const float*)d_in[20];
    const float* tc2b2 = (const float*)d_in[21];
    float* out = (float*)d_out;

    char* p = (char*)d_ws;
    f16*   xT    = (f16*)p;   p += (size_t)NN * CCH * TIN * 2;
    f16*   out0h = (f16*)p;   p += (size_t)NN * FF * 2;
    f16*   h1    = (f16*)p;   p += (size_t)NN * FF * 2;
    f16*   h2    = (f16*)p;   p += (size_t)NN * FF * 2;
    f16*   h3    = (f16*)p;   p += (size_t)NN * FF * 2;
    f16*   hneg  = (f16*)p;   p += (size_t)NN * FF * 2;
    f16*   Cb16  = (f16*)p;   p += (size_t)NN * FF * 2;
    f16*   Gbuf  = (f16*)p;   p += (size_t)NN * FF * 2;
    f16*   Wtp   = (f16*)p;   p += (size_t)FF * FF * 2;
    f16*   Wtn   = (f16*)p;   p += (size_t)FF * FF * 2;
    f16*   Wtmp  = (f16*)p;   p += (size_t)FF * FF * 2;
    f16*   gWt   = (f16*)p;   p += (size_t)128 * 64 * 2;
    f16*   Bw1   = (f16*)p;   p += (size_t)128 * 192 * 2;
    f16*   Bw2   = (f16*)p;   p += (size_t)128 * 192 * 2;
    float* psib  = (float*)p; p += (size_t)NN * 3 * 4;
    float* degp  = (float*)p; p += (size_t)NN * 4;
    float* degn  = (float*)p; p += (size_t)NN * 4;
    float* disp  = (float*)p; p += (size_t)NN * 4;
    float* disn  = (float*)p; p += (size_t)NN * 4;
    float* normp = (float*)p; p += (size_t)NE * 4;
    float* normn = (float*)p; p += (size_t)NE * 4;
    int* cnt     = (int*)p;   p += (size_t)NN * 4;
    int* rowptr  = (int*)p;   p += (size_t)(NN + 1) * 4;
    int* cursor  = (int*)p;   p += (size_t)NN * 4;
    int* colsrc  = (int*)p;   p += (size_t)NE * 4;

    (void)hipMemsetAsync(cnt, 0, NN * 4, stream);
    (void)hipMemsetAsync(cursor, 0, NN * 4, stream);
    (void)hipMemsetAsync(degp, 0, NN * 4, stream);
    (void)hipMemsetAsync(degn, 0, NN * 4, stream);

    k_xT<<<2500, 256, 0, stream>>>(x, xT);
    k_wconv<<<(128 * 192 + 255) / 256, 256, 0, stream>>>(tc1w1, tc1w2, Bw1);
    k_wconv<<<(128 * 192 + 255) / 256, 256, 0, stream>>>(tc2w1, tc2w2, Bw2);
    k_tcn1g<<<(NR + 127) / 128, 256, 0, stream>>>(xT, Bw1, tc1b1, tc1b2, out0h);
    k_psi<<<(NN + 255) / 256, 256, 0, stream>>>(ndt, psiW1, psib1, psiW2, psib2, psib);
    k_deg<<<(NE + 255) / 256, 256, 0, stream>>>(ei, ea, cnt, degp, degn);
    k_dis<<<(NN + 255) / 256, 256, 0, stream>>>(degp, degn, disp, disn);
    k_scan<<<1, 1024, 0, stream>>>(cnt, rowptr);
    k_fill<<<(NE + 255) / 256, 256, 0, stream>>>(ei, ea, rowptr, cursor, disp, disn,
                                                 colsrc, normp, normn);
    dim3 wgrid(20, 20);
    k_wsplit<<<wgrid, 256, 0, stream>>>(Wpos, Wtmp);
    k_perm<<<FF, 640, 0, stream>>>(Wtmp, Wtp);
    k_wsplit<<<wgrid, 256, 0, stream>>>(Wneg, Wtmp);
    k_perm<<<FF, 640, 0, stream>>>(Wtmp, Wtn);
    k_gwt<<<(128 * 64 + 255) / 256, 256, 0, stream>>>(greW, gWt);

    dim3 ggrid((NN + 127) / 128, FF / 64);
    // positive hops
    k_gemm16<<<ggrid, 256, 0, stream>>>(out0h, Wtp, Cb16, NN);
    k_agg<<<NN, 320, 0, stream>>>(Cb16, rowptr, colsrc, normp, disp, bpos, h1);
    k_gemm16<<<ggrid, 256, 0, stream>>>(h1, Wtp, Cb16, NN);
    k_agg<<<NN, 320, 0, stream>>>(Cb16, rowptr, colsrc, normp, disp, bpos, h2);
    k_gemm16<<<ggrid, 256, 0, stream>>>(h2, Wtp, Cb16, NN);
    k_agg<<<NN, 320, 0, stream>>>(Cb16, rowptr, colsrc, normp, disp, bpos, h3);
    // negative branch
    k_gemm16<<<ggrid, 256, 0, stream>>>(out0h, Wtn, Cb16, NN);
    k_agg<<<NN, 320, 0, stream>>>(Cb16, rowptr, colsrc, normn, disn, bneg, hneg);
    // GReTo channel mix (MFMA) + psi accumulation + relu -> f16
    k_greto2<<<(NR + 127) / 128, 256, 0, stream>>>(h1, h2, h3, hneg, psib, gWt, greb, Gbuf);
    // final gated TCN as direct GEMM
    k_tcn2g<<<(NR2 + 127) / 128, 256, 0, stream>>>(Gbuf, Bw2, tc2b1, tc2b2, out);
}